// Round 4
// baseline (900.855 us; speedup 1.0000x reference)
//
#include <hip/hip_runtime.h>
#include <hip/hip_bf16.h>
#include <stdint.h>

typedef __attribute__((ext_vector_type(8))) short short8;
typedef __attribute__((ext_vector_type(4))) float f32x4;

#define AS1 __attribute__((address_space(1)))
#define AS3 __attribute__((address_space(3)))

#define NEL 1601978   // 1778*901
#define NROWS 1778
#define OUTF 901
#define CAMNB 783     // ceil(NEL / (256*8))

__device__ __forceinline__ float b2f(__hip_bfloat16 x) { return __bfloat162float(x); }
__device__ __forceinline__ __hip_bfloat16 f2b(float x) { return __float2bfloat16(x); }
__device__ __forceinline__ float sane(float v) { return isfinite(v) ? v : 0.f; }

// dtype-dual load: flag==1 -> fp32 array, flag==0 -> bf16 array
__device__ __forceinline__ float ldf(const void* p, long i, int f32)
{
    return f32 ? ((const float*)p)[i] : b2f(((const __hip_bfloat16*)p)[i]);
}

// 8-wide vector loads (base must be 8-aligned in elements)
__device__ __forceinline__ void ld8b(const __hip_bfloat16* p, long base, float* out)
{
    short8 t = *(const short8*)(p + base);
#pragma unroll
    for (int e = 0; e < 8; ++e) out[e] = __uint_as_float(((uint)(ushort)t[e]) << 16);
}
__device__ __forceinline__ void ld8d(const void* p, long base, int f32, float* out)
{
    if (f32) {
        const float4* q = (const float4*)((const float*)p + base);
        float4 a = q[0], b = q[1];
        out[0]=a.x; out[1]=a.y; out[2]=a.z; out[3]=a.w;
        out[4]=b.x; out[5]=b.y; out[6]=b.z; out[7]=b.w;
    } else {
        short8 t = *(const short8*)((const __hip_bfloat16*)p + base);
#pragma unroll
        for (int e = 0; e < 8; ++e) out[e] = __uint_as_float(((uint)(ushort)t[e]) << 16);
    }
}

// ---------------- dtype probe ----------------
__global__ void probe_dtype(const ushort* __restrict__ p, int* __restrict__ fdt)
{
    int t = threadIdx.x;
    int cnt = 0;
    for (int i = t; i < 512; i += 256) {
        int ex = (p[i] >> 7) & 0xFF;
        if (ex >= 0x85) cnt++;
    }
    for (int o = 32; o; o >>= 1) cnt += __shfl_down(cnt, o);
    __shared__ int s[4];
    if ((t & 63) == 0) s[t >> 6] = cnt;
    __syncthreads();
    if (t == 0) fdt[0] = (s[0] + s[1] + s[2] + s[3] > 16) ? 1 : 0;
}

// ---------------- zero scratch ----------------
__global__ void zerof(float* __restrict__ p, int n)
{
    int i = blockIdx.x * 256 + threadIdx.x;
    if (i < n) p[i] = 0.f;
}

// ---------------- pack (fp32|bf16) -> padded bf16 ----------------
__global__ void pack_dual(__hip_bfloat16* __restrict__ dst, const void* __restrict__ src,
                          int rows_valid, int cols_valid, int src_ld, int dst_ld,
                          const int* __restrict__ fdt)
{
    int c = blockIdx.x * 256 + threadIdx.x;
    int r = blockIdx.y;
    if (c >= dst_ld) return;
    float v = 0.f;
    if (r < rows_valid && c < cols_valid) v = ldf(src, (long)r * src_ld + c, fdt[0]);
    dst[(long)r * dst_ld + c] = f2b(v);
}

// ---------------- vector-staged bf16 GEMM: C = A(M,K) * B(N,K)^T ----------------
// T1 XCD swizzle + T2 XOR-swizzle (round-2) + T4 counted-vmcnt 3-buffer
// pipeline (this round). Per iter t:
//   s_waitcnt vmcnt(4)   <- only buf[t]'s 4 per-thread loads must land;
//                           buf[t+1]'s stay in flight (never drain to 0)
//   s_barrier            <- raw barrier (no compiler vmcnt(0) drain)
//   stage buf[t+2]       <- prefetch distance 2: ~2 compute phases to land
//   compute buf[t]
// Buffer reuse safety: buf[t%3] is re-staged at iter t+1, AFTER the barrier
// that follows iter t's compute; MFMA issue consumes ds_read data before the
// barrier, and vmcnt(4)-before-barrier lands all threads' buf[t] DMA writes
// before any ds_read of buf[t].
// EPI 0: store bf16 C[m*ldc+n].  EPI 1: relu(C/l[m] + bias[n]) -> bf16 vout.
template<int EPI, int XMAJ>
__global__ __launch_bounds__(512)
void gemm_fast(const ushort* __restrict__ A, const ushort* __restrict__ B, int K,
               __hip_bfloat16* __restrict__ Cbf, int ldc,
               const float* __restrict__ lrow, const void* __restrict__ bias,
               __hip_bfloat16* __restrict__ vout, int Mvalid, int Nvalid,
               const int* __restrict__ fdt)
{
    __shared__ __align__(16) ushort sA[3][128 * 64];
    __shared__ __align__(16) ushort sB[3][128 * 64];
    const int tid = threadIdx.x;
    const int lane = tid & 63;
    const int wid = tid >> 6;          // 0..7
    const int wm = (wid >> 2) * 64;    // 2 wave rows (M)
    const int wn = (wid & 3) * 32;     // 4 wave cols (N)

    const int gx = gridDim.x, gy = gridDim.y;
    int lid = blockIdx.y * gx + blockIdx.x;
    int bx, by;
    const int n = gx * gy;
    if ((n & 7) == 0) {
        int q = n >> 3;
        int pos = (lid & 7) * q + (lid >> 3);
        if (XMAJ) { bx = pos / gy; by = pos - bx * gy; }
        else      { by = pos / gx; bx = pos - by * gx; }
    } else {
        bx = blockIdx.x; by = blockIdx.y;
    }
    const long m0 = (long)by * 128;
    const long n0 = (long)bx * 128;

    f32x4 acc[4][2];
#pragma unroll
    for (int i = 0; i < 4; ++i)
#pragma unroll
        for (int j = 0; j < 2; ++j) acc[i][j] = (f32x4){0.f, 0.f, 0.f, 0.f};

    const int rsub = lane >> 3;       // 0..7 row within 8-row slab
    const int csub = (lane & 7) * 8;  // LDS chunk (linear in lane, required)
    const int gsub = ((lane & 7) ^ rsub) * 8;  // pre-swizzled GLOBAL chunk
    const int kgrp = lane >> 4;       // 0..3 chunk group of this lane's frag
    const int rowf = lane & 15;
    const int rx = rowf & 7;          // read-side swizzle key

    // async direct-to-LDS staging: 4 global_load_lds per thread per tile
    auto stage = [&](int buf, int k0) {
#pragma unroll
        for (int it = 0; it < 2; ++it) {
            int r = wid * 16 + it * 8 + rsub;   // 8 waves x 16 rows = 128
            __builtin_amdgcn_global_load_lds(
                (const AS1 uint*)(const void*)(A + (m0 + r) * (long)K + k0 + gsub),
                (AS3 uint*)&sA[buf][r * 64 + csub], 16, 0, 0);
            __builtin_amdgcn_global_load_lds(
                (const AS1 uint*)(const void*)(B + (n0 + r) * (long)K + k0 + gsub),
                (AS3 uint*)&sB[buf][r * 64 + csub], 16, 0, 0);
        }
    };

    const int nsteps = K >> 6;
    stage(0, 0);
    if (nsteps > 1) stage(1, 64);

    for (int t = 0; t < nsteps; ++t) {
        if (t + 1 < nsteps) asm volatile("s_waitcnt vmcnt(4)" ::: "memory");
        else                asm volatile("s_waitcnt vmcnt(0)" ::: "memory");
        __builtin_amdgcn_s_barrier();
        if (t + 2 < nsteps) stage((t + 2) % 3, (t + 2) * 64);

        const ushort* cA = &sA[t % 3][0];
        const ushort* cB = &sB[t % 3][0];
#pragma unroll
        for (int ks = 0; ks < 64; ks += 32) {
            short8 af[4], bfr[2];
            const int kc = (ks >> 3) + kgrp;        // logical 16B chunk 0..7
            const int kb = ((kc ^ rx) << 3);        // swizzled storage offset
#pragma unroll
            for (int f = 0; f < 4; ++f)
                af[f]  = *(const short8*)(&cA[(wm + f * 16 + rowf) * 64 + kb]);
#pragma unroll
            for (int f = 0; f < 2; ++f)
                bfr[f] = *(const short8*)(&cB[(wn + f * 16 + rowf) * 64 + kb]);
#pragma unroll
            for (int i = 0; i < 4; ++i)
#pragma unroll
                for (int j = 0; j < 2; ++j)
                    acc[i][j] = __builtin_amdgcn_mfma_f32_16x16x32_bf16(af[i], bfr[j], acc[i][j], 0, 0, 0);
        }
    }

    const int f32 = (EPI == 1) ? fdt[0] : 0;
    const int rq = (lane >> 4) * 4;   // C/D: col = lane&15, row = (lane>>4)*4 + reg
#pragma unroll
    for (int i = 0; i < 4; ++i)
#pragma unroll
        for (int j = 0; j < 2; ++j)
#pragma unroll
            for (int rg = 0; rg < 4; ++rg) {
                long m = m0 + wm + i * 16 + rq + rg;
                long n2 = n0 + wn + j * 16 + (lane & 15);
                float v = acc[i][j][rg];
                if constexpr (EPI == 0) {
                    Cbf[m * ldc + n2] = f2b(v);
                } else {
                    if (m < Mvalid && n2 < Nvalid) {
                        float den = fmaxf(lrow[m], 1e-30f);
                        float r = v / den + ldf(bias, n2, f32);
                        vout[m * Nvalid + n2] = f2b(sane(fmaxf(r, 0.f)));
                    }
                }
            }
}

// ---------------- GEMM1 fallback: raw operands, dtype-dual scalar staging ----------------
__global__ __launch_bounds__(256)
void gemm1_raw(const void* __restrict__ A, const void* __restrict__ B, int K,
               int lda, int ldb, int Ma, int Nb, int Kv,
               __hip_bfloat16* __restrict__ Cbf, int ldc, const int* __restrict__ fdt)
{
    __shared__ __align__(16) ushort sA[128 * 64];
    __shared__ __align__(16) ushort sB[128 * 64];
    const int f32 = fdt[0];
    const int tid = threadIdx.x;
    const int lane = tid & 63;
    const int wid = tid >> 6;
    const int wm = (wid >> 1) * 64;
    const int wn = (wid & 1) * 64;
    const long m0 = (long)blockIdx.y * 128;
    const long n0 = (long)blockIdx.x * 128;

    f32x4 acc[4][4];
#pragma unroll
    for (int i = 0; i < 4; ++i)
#pragma unroll
        for (int j = 0; j < 4; ++j) acc[i][j] = (f32x4){0.f, 0.f, 0.f, 0.f};

    const int lr = tid >> 3;
    const int lc = (tid & 7) * 8;
    const int koff = (lane >> 4) * 8;
    const int rowf = lane & 15;

    for (int k0 = 0; k0 < K; k0 += 64) {
        __syncthreads();
#pragma unroll
        for (int it = 0; it < 4; ++it) {
            int r = it * 32 + lr;
            long gm = m0 + r, gn = n0 + r;
            ushort va[8], vb[8];
#pragma unroll
            for (int e = 0; e < 8; ++e) {
                int k = k0 + lc + e;
                bool kok = (k < Kv);
                float fa = (kok && gm < Ma) ? ldf(A, gm * (long)lda + k, f32) : 0.f;
                float fb = (kok && gn < Nb) ? ldf(B, gn * (long)ldb + k, f32) : 0.f;
                va[e] = __hip_bfloat16_raw(f2b(fa)).x;
                vb[e] = __hip_bfloat16_raw(f2b(fb)).x;
            }
#pragma unroll
            for (int e = 0; e < 8; ++e) { sA[r * 64 + lc + e] = va[e]; sB[r * 64 + lc + e] = vb[e]; }
        }
        __syncthreads();
#pragma unroll
        for (int ks = 0; ks < 64; ks += 32) {
            short8 af[4], bfr[4];
            int kb = ks + koff;
#pragma unroll
            for (int f = 0; f < 4; ++f) {
                af[f]  = *(const short8*)(&sA[(wm + f * 16 + rowf) * 64 + kb]);
                bfr[f] = *(const short8*)(&sB[(wn + f * 16 + rowf) * 64 + kb]);
            }
#pragma unroll
            for (int i = 0; i < 4; ++i)
#pragma unroll
                for (int j = 0; j < 4; ++j)
                    acc[i][j] = __builtin_amdgcn_mfma_f32_16x16x32_bf16(af[i], bfr[j], acc[i][j], 0, 0, 0);
        }
    }

    const int rq = (lane >> 4) * 4;
#pragma unroll
    for (int i = 0; i < 4; ++i)
#pragma unroll
        for (int j = 0; j < 4; ++j)
#pragma unroll
            for (int rg = 0; rg < 4; ++rg) {
                long m = m0 + wm + i * 16 + rq + rg;
                long n = n0 + wn + j * 16 + (lane & 15);
                Cbf[m * ldc + n] = f2b(acc[i][j][rg]);
            }
}

// ---------------- asrc/adst: parallel over (j, o-chunks), atomic accumulate ----------------
__global__ void srcdst2(const __hip_bfloat16* __restrict__ hT,
                        const void* __restrict__ a_src, const void* __restrict__ a_dst,
                        int Nv, int Nvp, float* __restrict__ asrc, float* __restrict__ adst,
                        const int* __restrict__ fdt)
{
    const int f32 = fdt[0];
    int j = blockIdx.x * 256 + threadIdx.x;
    if (j >= Nv) return;
    int o0 = blockIdx.y * 113;
    int o1 = min(OUTF, o0 + 113);
    float s1 = 0.f, s2 = 0.f;
    for (int o = o0; o < o1; ++o) {
        float hv = b2f(hT[(long)o * Nvp + j]);
        s1 += hv * ldf(a_src, o, f32);
        s2 += hv * ldf(a_dst, o, f32);
    }
    atomicAdd(&asrc[j], s1);
    atomicAdd(&adst[j], s2);
}

// ---------------- P = mask * exp(leaky(adst_i + asrc_j)), row sums l ----------------
// adj tile staged through LDS so global adj reads are coalesced along i.
__global__ void pbuild(const int* __restrict__ adj, const float* __restrict__ asrc,
                       const float* __restrict__ adst, int Nv, int Nvp, int ioff,
                       __hip_bfloat16* __restrict__ P, float* __restrict__ l)
{
    __shared__ int sAdj[64][65];
    const int lane = threadIdx.x & 63, grp = threadIdx.x >> 6;
    const int j0 = blockIdx.x * 64, r0 = blockIdx.y * 64;

    // Phase A: sAdj[jr][c] = adj[(j0+jr)*Nv + i(r0+c)], coalesced (lane = c)
    {
        int r_lane = r0 + lane;
        bool rv = (r_lane < NROWS);
        int i_lane = (r_lane < 901) ? r_lane : r_lane + ioff;   // < Nv when rv
#pragma unroll
        for (int it = 0; it < 16; ++it) {
            int jr = it * 4 + grp;
            int j = j0 + jr;
            int v = 0;
            if (j < Nv && rv) v = adj[(long)j * Nv + i_lane];
            sAdj[jr][lane] = v;
        }
    }
    __syncthreads();

    // Phase B: original compute, lane = j; mask from sAdj[lane][rr]
    const int j = j0 + lane;
    const float as = (j < Nv) ? asrc[j] : 0.f;
#pragma unroll
    for (int it = 0; it < 16; ++it) {
        int rr = it * 4 + grp;
        int r = r0 + rr;
        int i = (r < 901) ? r : r + ioff;
        float p = 0.f;
        if (r < NROWS && j < Nv) {
            bool m = (sAdj[lane][rr] != 0) || (i == j);
            if (m) {
                float e = adst[i] + as;
                e = e > 0.f ? e : 0.2f * e;
                p = expf(fminf(e, 30.f));
            }
        }
        __hip_bfloat16 pb = f2b(p);
        if (r < 1792) P[(long)r * Nvp + j] = pb;
        float pv = b2f(pb);
        for (int o = 32; o; o >>= 1) pv += __shfl_down(pv, o);
        if (lane == 0 && r < NROWS) atomicAdd(&l[r], pv);
    }
}

// ---------------- CAM (vectorized, zero-atomic two-stage reduction) ----------------
__device__ __forceinline__ void block_part4(float a, float b, float c, float d, float4* out)
{
    for (int o = 32; o; o >>= 1) {
        a += __shfl_down(a, o); b += __shfl_down(b, o);
        c += __shfl_down(c, o); d += __shfl_down(d, o);
    }
    __shared__ float s[4][4];
    int lane = threadIdx.x & 63, wv = threadIdx.x >> 6;
    if (lane == 0) { s[wv][0] = a; s[wv][1] = b; s[wv][2] = c; s[wv][3] = d; }
    __syncthreads();
    if (threadIdx.x == 0)
        *out = make_float4(s[0][0] + s[1][0] + s[2][0] + s[3][0],
                           s[0][1] + s[1][1] + s[2][1] + s[3][1],
                           s[0][2] + s[1][2] + s[2][2] + s[3][2],
                           s[0][3] + s[1][3] + s[2][3] + s[3][3]);
}

__device__ __forceinline__ void camY(int idx,
    const __hip_bfloat16* v0, const __hip_bfloat16* v1, const __hip_bfloat16* v2,
    const void* md, const void* lw1, const void* lb1, const void* gw1, const void* gb1,
    int f32, float& Yl, float& Yg)
{
    float x0 = b2f(v0[idx]), x1 = b2f(v1[idx]), x2 = b2f(v2[idx]), x3 = ldf(md, idx, f32);
    Yl = ldf(lw1,0,f32)*x0 + ldf(lw1,1,f32)*x1 + ldf(lw1,2,f32)*x2 + ldf(lw1,3,f32)*x3 + ldf(lb1,0,f32);
    Yg = ldf(gw1,0,f32)*x0 + ldf(gw1,1,f32)*x1 + ldf(gw1,2,f32)*x2 + ldf(gw1,3,f32)*x3 + ldf(gb1,0,f32);
}

// vector camY: 8 elements at base (base%8==0, base+8<=NEL)
__device__ __forceinline__ void camY8(long base,
    const __hip_bfloat16* v0, const __hip_bfloat16* v1, const __hip_bfloat16* v2,
    const void* md, const void* lw1, const void* lb1, const void* gw1, const void* gb1,
    int f32, float* Yl, float* Yg, float x[4][8])
{
    ld8b(v0, base, x[0]); ld8b(v1, base, x[1]); ld8b(v2, base, x[2]);
    ld8d(md, base, f32, x[3]);
    float wl0 = ldf(lw1,0,f32), wl1 = ldf(lw1,1,f32), wl2 = ldf(lw1,2,f32), wl3 = ldf(lw1,3,f32);
    float wg0 = ldf(gw1,0,f32), wg1 = ldf(gw1,1,f32), wg2 = ldf(gw1,2,f32), wg3 = ldf(gw1,3,f32);
    float bl = ldf(lb1,0,f32), bg = ldf(gb1,0,f32);
#pragma unroll
    for (int e = 0; e < 8; ++e) {
        Yl[e] = wl0*x[0][e] + wl1*x[1][e] + wl2*x[2][e] + wl3*x[3][e] + bl;
        Yg[e] = wg0*x[0][e] + wg1*x[1][e] + wg2*x[2][e] + wg3*x[3][e] + bg;
    }
}

__global__ void cam_pass1(const __hip_bfloat16* __restrict__ v0, const __hip_bfloat16* __restrict__ v1,
                          const __hip_bfloat16* __restrict__ v2, const void* __restrict__ md,
                          const void* __restrict__ lw1, const void* __restrict__ lb1,
                          const void* __restrict__ gw1, const void* __restrict__ gb1,
                          float4* __restrict__ part, const int* __restrict__ fdt)
{
    long base = ((long)blockIdx.x * 256 + threadIdx.x) * 8;
    float a = 0, b = 0, c = 0, d = 0;
    const int f32 = fdt[0];
    if (base + 8 <= NEL) {
        float Yl[8], Yg[8], x[4][8];
        camY8(base, v0, v1, v2, md, lw1, lb1, gw1, gb1, f32, Yl, Yg, x);
#pragma unroll
        for (int e = 0; e < 8; ++e) { a += Yl[e]; b += Yl[e]*Yl[e]; c += Yg[e]; d += Yg[e]*Yg[e]; }
    } else if (base < NEL) {
        for (long i = base; i < NEL; ++i) {
            float Yl, Yg;
            camY((int)i, v0, v1, v2, md, lw1, lb1, gw1, gb1, f32, Yl, Yg);
            a += Yl; b += Yl*Yl; c += Yg; d += Yg*Yg;
        }
    }
    block_part4(a, b, c, d, &part[blockIdx.x]);
}

__global__ void cam_fin1(const float4* __restrict__ part, float* __restrict__ sF)
{
    int t = threadIdx.x;
    double a = 0, b = 0, c = 0, d = 0;
    for (int i = t; i < CAMNB; i += 256) {
        float4 p = part[i];
        a += p.x; b += p.y; c += p.z; d += p.w;
    }
    for (int o = 32; o; o >>= 1) {
        a += __shfl_down(a, o); b += __shfl_down(b, o);
        c += __shfl_down(c, o); d += __shfl_down(d, o);
    }
    __shared__ double sd[4][4];
    int lane = t & 63, wv = t >> 6;
    if (!lane) { sd[wv][0] = a; sd[wv][1] = b; sd[wv][2] = c; sd[wv][3] = d; }
    __syncthreads();
    if (t == 0) {
        double n = (double)NEL;
        double A = sd[0][0]+sd[1][0]+sd[2][0]+sd[3][0];
        double B = sd[0][1]+sd[1][1]+sd[2][1]+sd[3][1];
        double C = sd[0][2]+sd[1][2]+sd[2][2]+sd[3][2];
        double D = sd[0][3]+sd[1][3]+sd[2][3]+sd[3][3];
        double ml = A / n, vl = B / n - ml * ml;
        double mg = C / n, vg = D / n - mg * mg;
        if (vl < 0.0) vl = 0.0;
        if (vg < 0.0) vg = 0.0;
        sF[0] = (float)ml; sF[1] = (float)(1.0 / sqrt(vl + 1e-5));
        sF[2] = (float)mg; sF[3] = (float)(1.0 / sqrt(vg + 1e-5));
    }
}

__global__ void cam_pass2(const __hip_bfloat16* __restrict__ v0, const __hip_bfloat16* __restrict__ v1,
                          const __hip_bfloat16* __restrict__ v2, const void* __restrict__ md,
                          const void* __restrict__ lw1, const void* __restrict__ lb1,
                          const void* __restrict__ gw1, const void* __restrict__ gb1,
                          const float* __restrict__ sF, float4* __restrict__ part,
                          const int* __restrict__ fdt)
{
    long base = ((long)blockIdx.x * 256 + threadIdx.x) * 8;
    float a = 0, b = 0, c = 0, d = 0;
    const int f32 = fdt[0];
    const float m_l = sF[0], is_l = sF[1], m_g = sF[2], is_g = sF[3];
    if (base + 8 <= NEL) {
        float Yl[8], Yg[8], x[4][8];
        camY8(base, v0, v1, v2, md, lw1, lb1, gw1, gb1, f32, Yl, Yg, x);
#pragma unroll
        for (int e = 0; e < 8; ++e) {
            float zl = fmaxf((Yl[e] - m_l) * is_l, 0.f);
            float zg = fmaxf((Yg[e] - m_g) * is_g, 0.f);
            a += zl; b += zl*zl; c += zg; d += zg*zg;
        }
    } else if (base < NEL) {
        for (long i = base; i < NEL; ++i) {
            float Yl, Yg;
            camY((int)i, v0, v1, v2, md, lw1, lb1, gw1, gb1, f32, Yl, Yg);
            float zl = fmaxf((Yl - m_l) * is_l, 0.f);
            float zg = fmaxf((Yg - m_g) * is_g, 0.f);
            a += zl; b += zl*zl; c += zg; d += zg*zg;
        }
    }
    block_part4(a, b, c, d, &part[blockIdx.x]);
}

__global__ void cam_fin2(const float4* __restrict__ part, float* __restrict__ sF,
                         const void* __restrict__ lw2, const void* __restrict__ gw2,
                         const int* __restrict__ fdt)
{
    int t = threadIdx.x;
    double a = 0, b = 0, c = 0, d = 0;
    for (int i = t; i < CAMNB; i += 256) {
        float4 p = part[i];
        a += p.x; b += p.y; c += p.z; d += p.w;
    }
    for (int o = 32; o; o >>= 1) {
        a += __shfl_down(a, o); b += __shfl_down(b, o);
        c += __shfl_down(c, o); d += __shfl_down(d, o);
    }
    __shared__ double sd[4][4];
    int lane = t & 63, wv = t >> 6;
    if (!lane) { sd[wv][0] = a; sd[wv][1] = b; sd[wv][2] = c; sd[wv][3] = d; }
    __syncthreads();
    if (t == 0) {
        const int f32 = fdt[0];
        double n = (double)NEL;
        double A = sd[0][0]+sd[1][0]+sd[2][0]+sd[3][0];
        double B = sd[0][1]+sd[1][1]+sd[2][1]+sd[3][1];
        double C = sd[0][2]+sd[1][2]+sd[2][2]+sd[3][2];
        double D = sd[0][3]+sd[1][3]+sd[2][3]+sd[3][3];
        double mzl = A / n, vzl = B / n - mzl * mzl;
        double mzg = C / n, vzg = D / n - mzg * mzg;
        if (vzl < 0.0) vzl = 0.0;
        if (vzg < 0.0) vzg = 0.0;
        sF[4] = (float)mzl; sF[5] = (float)mzg;
        for (int c2 = 0; c2 < 4; ++c2) {
            double wl = (double)ldf(lw2, c2, f32);
            double wg = (double)ldf(gw2, c2, f32);
            sF[6 + c2]  = (float)(wl / sqrt(wl * wl * vzl + 1e-5));
            sF[10 + c2] = (float)(wg / sqrt(wg * wg * vzg + 1e-5));
        }
    }
}

__global__ void cam_fuse(const __hip_bfloat16* __restrict__ v0, const __hip_bfloat16* __restrict__ v1,
                         const __hip_bfloat16* __restrict__ v2, const void* __restrict__ md,
                         const void* __restrict__ lw1, const void* __restrict__ lb1,
                         const void* __restrict__ gw1, const void* __restrict__ gb1,
                         const float* __restrict__ sF, float* __restrict__ sumx,
                         const int* __restrict__ fdt)
{
    long base = ((long)blockIdx.x * 256 + threadIdx.x) * 8;
    if (base >= NEL) return;
    const int f32 = fdt[0];
    const float m_l = sF[0], is_l = sF[1], m_g = sF[2], is_g = sF[3];
    const float mzl = sF[4], mzg = sF[5];
    float wl2[4], wg2[4];
#pragma unroll
    for (int c = 0; c < 4; ++c) { wl2[c] = sF[6 + c]; wg2[c] = sF[10 + c]; }

    if (base + 8 <= NEL) {
        float Yl[8], Yg[8], x[4][8], sv[8];
        camY8(base, v0, v1, v2, md, lw1, lb1, gw1, gb1, f32, Yl, Yg, x);
#pragma unroll
        for (int e = 0; e < 8; ++e) {
            float zl = fmaxf((Yl[e] - m_l) * is_l, 0.f);
            float zg = fmaxf((Yg[e] - m_g) * is_g, 0.f);
            float dzl = zl - mzl, dzg = zg - mzg;
            float s = 0.f;
#pragma unroll
            for (int c = 0; c < 4; ++c) {
                float t2 = wl2[c] * dzl + wg2[c] * dzg;
                s += x[c][e] / (1.f + expf(-t2));
            }
            sv[e] = 0.25f * s;
        }
        *(float4*)(sumx + base)     = make_float4(sv[0], sv[1], sv[2], sv[3]);
        *(float4*)(sumx + base + 4) = make_float4(sv[4], sv[5], sv[6], sv[7]);
    } else {
        for (long i = base; i < NEL; ++i) {
            float Yl, Yg;
            camY((int)i, v0, v1, v2, md, lw1, lb1, gw1, gb1, f32, Yl, Yg);
            float zl = fmaxf((Yl - m_l) * is_l, 0.f);
            float zg = fmaxf((Yg - m_g) * is_g, 0.f);
            float dzl = zl - mzl, dzg = zg - mzg;
            float xx[4] = {b2f(v0[i]), b2f(v1[i]), b2f(v2[i]), ldf(md, i, f32)};
            float s = 0.f;
#pragma unroll
            for (int c = 0; c < 4; ++c) {
                float t2 = wl2[c] * dzl + wg2[c] * dzg;
                s += xx[c] / (1.f + expf(-t2));
            }
            sumx[i] = 0.25f * s;
        }
    }
}

// ---------------- collapsed MLP head (parallel, multi-kernel) ----------------
__global__ void mlp_a(const void* __restrict__ mW3, const void* __restrict__ mW4,
                      const void* __restrict__ mb2, const void* __restrict__ mb3,
                      const void* __restrict__ mb4,
                      float* __restrict__ u3g, float* __restrict__ u2g,
                      float* __restrict__ sF, const int* __restrict__ fdt)
{
    __shared__ float u3[64];
    __shared__ float red[4];
    const int f32 = fdt[0];
    int t = threadIdx.x;
    if (t < 64) { float v = ldf(mW4, t, f32); u3[t] = v; u3g[t] = v; }
    __syncthreads();
    float part = 0.f;
    for (int k = t; k < 512; k += 256) {
        float s = 0.f;
#pragma unroll
        for (int o = 0; o < 64; ++o) s += ldf(mW3, o * 512 + k, f32) * u3[o];
        u2g[k] = s;
        part += ldf(mb2, k, f32) * s;
    }
    if (t < 64) part += ldf(mb3, t, f32) * u3[t];
    for (int o = 32; o; o >>= 1) part += __shfl_down(part, o);
    if ((t & 63) == 0) red[t >> 6] = part;
    __syncthreads();
    if (t == 0) sF[15] = red[0] + red[1] + red[2] + red[3] + ldf(mb4, 0, f32);
}

__global__ void mlp_b1(const void* __restrict__ mW2, const float* __restrict__ u2g,
                       float* __restrict__ part1, const int* __restrict__ fdt)
{
    int k = blockIdx.x * 256 + threadIdx.x;
    int o0 = blockIdx.y * 64;
    const int f32 = fdt[0];
    float s = 0.f;
#pragma unroll
    for (int oi = 0; oi < 64; ++oi) s += ldf(mW2, (long)(o0 + oi) * 1024 + k, f32) * u2g[o0 + oi];
    part1[blockIdx.y * 1024 + k] = s;
}

__global__ void mlp_b2(const float* __restrict__ part1, float* __restrict__ u1g)
{
    int k = blockIdx.x * 256 + threadIdx.x;
    float s = 0.f;
#pragma unroll
    for (int ob = 0; ob < 8; ++ob) s += part1[ob * 1024 + k];
    u1g[k] = s;
}

__global__ void mlp_c(const void* __restrict__ mb1, const float* __restrict__ u1g,
                      float* __restrict__ sF, const int* __restrict__ fdt)
{
    __shared__ float red[4];
    int t = threadIdx.x;
    const int f32 = fdt[0];
    float p = 0.f;
    for (int k = t; k < 1024; k += 256) p += ldf(mb1, k, f32) * u1g[k];
    for (int o = 32; o; o >>= 1) p += __shfl_down(p, o);
    if ((t & 63) == 0) red[t >> 6] = p;
    __syncthreads();
    if (t == 0) sF[14] = sF[15] + red[0] + red[1] + red[2] + red[3];
}

__global__ void mlp_u0s1(const void* __restrict__ mW1, const float* __restrict__ u1g,
                         float* __restrict__ part0, const int* __restrict__ fdt)
{
    int k = blockIdx.x * 256 + threadIdx.x;
    if (k >= 1802) return;
    int o0 = blockIdx.y * 64;
    const int f32 = fdt[0];
    float s = 0.f;
#pragma unroll
    for (int oi = 0; oi < 64; ++oi) s += ldf(mW1, (long)(o0 + oi) * 1802 + k, f32) * u1g[o0 + oi];
    part0[blockIdx.y * 2048 + k] = s;
}

__global__ void mlp_u0s2(const float* __restrict__ part0, float* __restrict__ u0)
{
    int k = blockIdx.x * 256 + threadIdx.x;
    if (k >= 1802) return;
    float s = 0.f;
#pragma unroll
    for (int ob = 0; ob < 16; ++ob) s += part0[ob * 2048 + k];
    u0[k] = s;
}

__global__ void rowdot(const float* __restrict__ sumx, const float* __restrict__ u0,
                       float* __restrict__ f, float* __restrict__ g)
{
    int r = blockIdx.x, t = threadIdx.x;
    float fa = 0.f, ga = 0.f;
    for (int o = t; o < OUTF; o += 256) {
        float v = sumx[(long)r * OUTF + o];
        fa += v * u0[o];
        ga += v * u0[OUTF + o];
    }
    for (int o = 32; o; o >>= 1) { fa += __shfl_down(fa, o); ga += __shfl_down(ga, o); }
    __shared__ float s[4][2];
    int lane = t & 63, wv = t >> 6;
    if (!lane) { s[wv][0] = fa; s[wv][1] = ga; }
    __syncthreads();
    if (t == 0) {
        f[r] = s[0][0] + s[1][0] + s[2][0] + s[3][0];
        g[r] = s[0][1] + s[1][1] + s[2][1] + s[3][1];
    }
}

__global__ void score(const int* __restrict__ ts, const float* __restrict__ f,
                      const float* __restrict__ g, const float* __restrict__ sF,
                      void* __restrict__ out, const int* __restrict__ fdt)
{
    int p = blockIdx.x * 256 + threadIdx.x;
    if (p >= 4096) return;
    float v = sane(f[ts[2 * p]] + g[ts[2 * p + 1]] + sF[14]);
    if (fdt[0]) ((float*)out)[p] = v;
    else        ((__hip_bfloat16*)out)[p] = f2b(v);
}

// ---------------- launch ----------------
extern "C" void kernel_launch(void* const* d_in, const int* in_sizes, int n_in,
                              void* d_out, int out_size, void* d_ws, size_t ws_size,
                              hipStream_t stream)
{
    const int NVv[3]   = {2060, 2459, 3929};
    const int NVPv[3]  = {2176, 2560, 3968};
    const int IOFFv[3] = {282, 681, 2151};
    const int ADJ_I[3] = {0, 1, 2}, FEAT_I[3] = {4, 5, 6}, W_I[3] = {8, 12, 16},
              AS_I[3] = {9, 13, 17}, AD_I[3] = {10, 14, 18}, BV_I[3] = {11, 15, 19};

    char* w = (char*)d_ws;
    size_t off = 0;
    auto alloc = [&](size_t b) { void* p = w + off; off += (b + 255) & ~(size_t)255; return p; };

    ushort* hT   = (ushort*)alloc(1024ULL * 3968 * 2);            // 8.1 MB
    ushort* Pexp = (ushort*)alloc(1792ULL * 3968 * 2);            // 14.2 MB
    __hip_bfloat16* voutb[3];
    for (int v = 0; v < 3; ++v)
        voutb[v] = (__hip_bfloat16*)alloc((size_t)NROWS * OUTF * 2);  // 3x 3.2 MB
    // asrc/adst/lrow contiguous (each size multiple of 256B) -> single zerof
    float*  asrc   = (float*)alloc(3968 * 4);
    float*  adst   = (float*)alloc(3968 * 4);
    float*  lrow   = (float*)alloc(1792 * 4);
    float*  statsF = (float*)alloc(16 * 4);
    float*  u3g    = (float*)alloc(64 * 4);
    float*  u2g    = (float*)alloc(512 * 4);
    float*  u1     = (float*)alloc(1024 * 4);
    float*  u0     = (float*)alloc(1802 * 4);
    float*  part1  = (float*)alloc(8 * 1024 * 4);
    float*  part0  = (float*)alloc(16 * 2048 * 4);
    float*  fv     = (float*)alloc(NROWS * 4);
    float*  gv     = (float*)alloc(NROWS * 4);
    int*    fdt    = (int*)alloc(4);
    float4* cp1    = (float4*)alloc(CAMNB * 16);
    float4* cp2    = (float4*)alloc(CAMNB * 16);
    // fast-path-only: featPad allocated last so the compact set fits small ws
    ushort* featPad = (ushort*)alloc(3968ULL * 3968 * 2);         // 31.5 MB
    const bool use_fast = (ws_size >= off);
    // overlays on dead regions
    ushort* Wpad = Pexp;            // Wpad (8.1 MB) lives in Pexp (14.2 MB) during gemm1
    float*  sumx = (float*)hT;      // hT dead after view loop; sumx 6.4 MB < 8.1 MB

    probe_dtype<<<1, 256, 0, stream>>>((const ushort*)d_in[9], fdt);

    for (int v = 0; v < 3; ++v) {
        int Nv = NVv[v], Nvp = NVPv[v], ioff2 = IOFFv[v];
        int Kp = (Nv + 63) & ~63;

        dim3 gg1(Nvp / 128, 8);   // hT[1024, Nvp] = W · feat^T
        if (use_fast) {
            dim3 gpk((Nvp + 255) / 256, Nvp);
            pack_dual<<<gpk, 256, 0, stream>>>((__hip_bfloat16*)featPad, d_in[FEAT_I[v]],
                                               Nv, Nv, Nv, Nvp, fdt);
            dim3 gpw((Nvp + 255) / 256, 1024);
            pack_dual<<<gpw, 256, 0, stream>>>((__hip_bfloat16*)Wpad, d_in[W_I[v]],
                                               901, Nv, Nv, Nvp, fdt);
            // B (featPad) is the big operand -> cluster same-x per XCD
            gemm_fast<0, 1><<<gg1, 512, 0, stream>>>(Wpad, featPad, Nvp,
                (__hip_bfloat16*)hT, Nvp, nullptr, nullptr, nullptr, 0, 0, fdt);
        } else {
            gemm1_raw<<<gg1, 256, 0, stream>>>(d_in[W_I[v]], d_in[FEAT_I[v]], Kp,
                                               Nv, Nv, 901, Nv, Nv,
                                               (__hip_bfloat16*)hT, Nvp, fdt);
        }

        // zero asrc+adst+lrow in one shot (contiguous: 3968+3968+1792 floats)
        zerof<<<38, 256, 0, stream>>>(asrc, 3968 + 3968 + 1792);

        dim3 gsd((Nv + 255) / 256, 8);
        srcdst2<<<gsd, 256, 0, stream>>>((const __hip_bfloat16*)hT,
            d_in[AS_I[v]], d_in[AD_I[v]], Nv, Nvp, asrc, adst, fdt);

        dim3 gp(Nvp / 64, 28);
        pbuild<<<gp, 256, 0, stream>>>((const int*)d_in[ADJ_I[v]], asrc, adst, Nv, Nvp, ioff2,
                                       (__hip_bfloat16*)Pexp, lrow);

        dim3 gg2(8, 14);          // vout[1778,901] = relu(P·h / l + b)
        // A (Pexp) is the big operand -> cluster same-y per XCD
        gemm_fast<1, 0><<<gg2, 512, 0, stream>>>(Pexp, hT, Nvp,
            nullptr, 0, lrow, d_in[BV_I[v]], voutb[v], NROWS, OUTF, fdt);
    }

    cam_pass1<<<CAMNB, 256, 0, stream>>>(voutb[0], voutb[1], voutb[2], d_in[7],
        d_in[20], d_in[21], d_in[24], d_in[25], cp1, fdt);
    cam_fin1<<<1, 256, 0, stream>>>(cp1, statsF);
    cam_pass2<<<CAMNB, 256, 0, stream>>>(voutb[0], voutb[1], voutb[2], d_in[7],
        d_in[20], d_in[21], d_in[24], d_in[25], statsF, cp2, fdt);
    cam_fin2<<<1, 256, 0, stream>>>(cp2, statsF, d_in[22], d_in[26], fdt);
    cam_fuse<<<CAMNB, 256, 0, stream>>>(voutb[0], voutb[1], voutb[2], d_in[7],
        d_in[20], d_in[21], d_in[24], d_in[25], statsF, sumx, fdt);

    // collapsed MLP head, parallelized
    mlp_a<<<1, 256, 0, stream>>>(d_in[32], d_in[34], d_in[31], d_in[33], d_in[35],
                                 u3g, u2g, statsF, fdt);
    mlp_b1<<<dim3(4, 8), 256, 0, stream>>>(d_in[30], u2g, part1, fdt);
    mlp_b2<<<4, 256, 0, stream>>>(part1, u1);
    mlp_c<<<1, 256, 0, stream>>>(d_in[29], u1, statsF, fdt);
    mlp_u0s1<<<dim3(8, 16), 256, 0, stream>>>(d_in[28], u1, part0, fdt);
    mlp_u0s2<<<8, 256, 0, stream>>>(part0, u0);

    rowdot<<<NROWS, 256, 0, stream>>>(sumx, u0, fv, gv);
    score<<<16, 256, 0, stream>>>((const int*)d_in[3], fv, gv, statsF, d_out, fdt);
}

// Round 5
// 817.067 us; speedup vs baseline: 1.1025x; 1.1025x over previous
//
#include <hip/hip_runtime.h>
#include <hip/hip_bf16.h>
#include <stdint.h>

typedef __attribute__((ext_vector_type(8))) short short8;
typedef __attribute__((ext_vector_type(4))) float f32x4;

#define AS1 __attribute__((address_space(1)))
#define AS3 __attribute__((address_space(3)))

#define NEL 1601978   // 1778*901
#define NROWS 1778
#define OUTF 901
#define CAMNB 783     // ceil(NEL / (256*8))

__device__ __forceinline__ float b2f(__hip_bfloat16 x) { return __bfloat162float(x); }
__device__ __forceinline__ __hip_bfloat16 f2b(float x) { return __float2bfloat16(x); }
__device__ __forceinline__ float sane(float v) { return isfinite(v) ? v : 0.f; }

// dtype-dual load: flag==1 -> fp32 array, flag==0 -> bf16 array
__device__ __forceinline__ float ldf(const void* p, long i, int f32)
{
    return f32 ? ((const float*)p)[i] : b2f(((const __hip_bfloat16*)p)[i]);
}

// 8-wide vector loads (base must be 8-aligned in elements)
__device__ __forceinline__ void ld8b(const __hip_bfloat16* p, long base, float* out)
{
    short8 t = *(const short8*)(p + base);
#pragma unroll
    for (int e = 0; e < 8; ++e) out[e] = __uint_as_float(((uint)(ushort)t[e]) << 16);
}
__device__ __forceinline__ void ld8d(const void* p, long base, int f32, float* out)
{
    if (f32) {
        const float4* q = (const float4*)((const float*)p + base);
        float4 a = q[0], b = q[1];
        out[0]=a.x; out[1]=a.y; out[2]=a.z; out[3]=a.w;
        out[4]=b.x; out[5]=b.y; out[6]=b.z; out[7]=b.w;
    } else {
        short8 t = *(const short8*)((const __hip_bfloat16*)p + base);
#pragma unroll
        for (int e = 0; e < 8; ++e) out[e] = __uint_as_float(((uint)(ushort)t[e]) << 16);
    }
}

// ---------------- dtype probe ----------------
__global__ void probe_dtype(const ushort* __restrict__ p, int* __restrict__ fdt)
{
    int t = threadIdx.x;
    int cnt = 0;
    for (int i = t; i < 512; i += 256) {
        int ex = (p[i] >> 7) & 0xFF;
        if (ex >= 0x85) cnt++;
    }
    for (int o = 32; o; o >>= 1) cnt += __shfl_down(cnt, o);
    __shared__ int s[4];
    if ((t & 63) == 0) s[t >> 6] = cnt;
    __syncthreads();
    if (t == 0) fdt[0] = (s[0] + s[1] + s[2] + s[3] > 16) ? 1 : 0;
}

// ---------------- zero scratch ----------------
__global__ void zerof(float* __restrict__ p, int n)
{
    int i = blockIdx.x * 256 + threadIdx.x;
    if (i < n) p[i] = 0.f;
}

// ---------------- pack (fp32|bf16) -> padded bf16 ----------------
__global__ void pack_dual(__hip_bfloat16* __restrict__ dst, const void* __restrict__ src,
                          int rows_valid, int cols_valid, int src_ld, int dst_ld,
                          const int* __restrict__ fdt)
{
    int c = blockIdx.x * 256 + threadIdx.x;
    int r = blockIdx.y;
    if (c >= dst_ld) return;
    float v = 0.f;
    if (r < rows_valid && c < cols_valid) v = ldf(src, (long)r * src_ld + c, fdt[0]);
    dst[(long)r * dst_ld + c] = f2b(v);
}

// ---------------- vector-staged bf16 GEMM: C = A(M,K) * B(N,K)^T ----------------
// Round-3 proven schedule (2-buffer, stage-before-compute, __syncthreads drain)
// REVERTED from the round-4 3-buffer/counted-vmcnt variant (regressed: MfmaUtil
// 19->7.6%, 63->69.6us). This round: BK 64->128 to halve per-step overhead
// (barrier + vmcnt(0) drain tail), which round-3 counters put at ~1400cy of the
// 2440cy step. Occupancy is grid-limited at 1 block/CU (all grids <= 248), so
// m132's BK=128 occupancy penalty does not apply. LDS = 2 x (32KB A + 32KB B)
// = 128KB. K must be %128==0 (all Nvp are: 2176/2560/3968).
// T2 swizzle generalized to 16 chunks/row: storage[r][c] = logical[r][c^(r&15)],
// pre-swizzled global source (LDS dest stays lane-linear, required by
// global_load_lds) + XOR'd ds_read chunk.
// T1 XCD swizzle unchanged.
// EPI 0: store bf16 C[m*ldc+n].  EPI 1: relu(C/l[m] + bias[n]) -> bf16 vout.
template<int EPI, int XMAJ>
__global__ __launch_bounds__(512)
void gemm_fast(const ushort* __restrict__ A, const ushort* __restrict__ B, int K,
               __hip_bfloat16* __restrict__ Cbf, int ldc,
               const float* __restrict__ lrow, const void* __restrict__ bias,
               __hip_bfloat16* __restrict__ vout, int Mvalid, int Nvalid,
               const int* __restrict__ fdt)
{
    __shared__ __align__(16) ushort sA[2][128 * 128];
    __shared__ __align__(16) ushort sB[2][128 * 128];
    const int tid = threadIdx.x;
    const int lane = tid & 63;
    const int wid = tid >> 6;          // 0..7
    const int wm = (wid >> 2) * 64;    // 2 wave rows (M)
    const int wn = (wid & 3) * 32;     // 4 wave cols (N)

    const int gx = gridDim.x, gy = gridDim.y;
    int lid = blockIdx.y * gx + blockIdx.x;
    int bx, by;
    const int n = gx * gy;
    if ((n & 7) == 0) {
        int q = n >> 3;
        int pos = (lid & 7) * q + (lid >> 3);
        if (XMAJ) { bx = pos / gy; by = pos - bx * gy; }
        else      { by = pos / gx; bx = pos - by * gx; }
    } else {
        bx = blockIdx.x; by = blockIdx.y;
    }
    const long m0 = (long)by * 128;
    const long n0 = (long)bx * 128;

    f32x4 acc[4][2];
#pragma unroll
    for (int i = 0; i < 4; ++i)
#pragma unroll
        for (int j = 0; j < 2; ++j) acc[i][j] = (f32x4){0.f, 0.f, 0.f, 0.f};

    const int rsub = lane >> 4;       // 0..3 row within 4-row slab
    const int cl   = lane & 15;       // 16B chunk slot within 256B row
    const int csub = cl * 8;          // LDS chunk offset (lane-linear, required)
    const int kgrp = lane >> 4;       // 0..3 k-chunk group of this lane's frag
    const int rowf = lane & 15;       // fragment row within 16

    // async direct-to-LDS staging of one 128x128 K-slab of A and B.
    // Per wave-instruction: 64 lanes x 16B = 4 rows x 256B, lane-linear LDS.
    // Global source chunk pre-XORed with (row & 15) -> storage = swizzled.
    auto stage = [&](int buf, int k0) {
#pragma unroll
        for (int it = 0; it < 4; ++it) {
            int rr = it * 4 + rsub;            // 0..15 == r & 15
            int r  = wid * 16 + rr;            // 8 waves x 16 rows = 128
            int gc = (cl ^ rr) * 8;            // pre-swizzled global chunk
            __builtin_amdgcn_global_load_lds(
                (const AS1 uint*)(const void*)(A + (m0 + r) * (long)K + k0 + gc),
                (AS3 uint*)&sA[buf][r * 128 + csub], 16, 0, 0);
            __builtin_amdgcn_global_load_lds(
                (const AS1 uint*)(const void*)(B + (n0 + r) * (long)K + k0 + gc),
                (AS3 uint*)&sB[buf][r * 128 + csub], 16, 0, 0);
        }
    };

    stage(0, 0);
    __syncthreads();                   // cold-start drain, once

    int cur = 0;
    for (int k0 = 0; k0 < K; k0 += 128) {
        if (k0 + 128 < K) stage(cur ^ 1, k0 + 128);   // prefetch next tile first
#pragma unroll
        for (int ks = 0; ks < 128; ks += 32) {
            short8 af[4], bfr[2];
            const int kc = (ks >> 3) + kgrp;        // logical 16B chunk 0..15
            const int kb = ((kc ^ rowf) << 3);      // swizzled storage offset
#pragma unroll
            for (int f = 0; f < 4; ++f)
                af[f]  = *(const short8*)(&sA[cur][(wm + f * 16 + rowf) * 128 + kb]);
#pragma unroll
            for (int f = 0; f < 2; ++f)
                bfr[f] = *(const short8*)(&sB[cur][(wn + f * 16 + rowf) * 128 + kb]);
#pragma unroll
            for (int i = 0; i < 4; ++i)
#pragma unroll
                for (int j = 0; j < 2; ++j)
                    acc[i][j] = __builtin_amdgcn_mfma_f32_16x16x32_bf16(af[i], bfr[j], acc[i][j], 0, 0, 0);
        }
        __syncthreads();   // drains vmcnt(0) (prefetch done) + lgkmcnt(0) (reads done)
        cur ^= 1;
    }

    const int f32 = (EPI == 1) ? fdt[0] : 0;
    const int rq = (lane >> 4) * 4;   // C/D: col = lane&15, row = (lane>>4)*4 + reg
#pragma unroll
    for (int i = 0; i < 4; ++i)
#pragma unroll
        for (int j = 0; j < 2; ++j)
#pragma unroll
            for (int rg = 0; rg < 4; ++rg) {
                long m = m0 + wm + i * 16 + rq + rg;
                long n2 = n0 + wn + j * 16 + (lane & 15);
                float v = acc[i][j][rg];
                if constexpr (EPI == 0) {
                    Cbf[m * ldc + n2] = f2b(v);
                } else {
                    if (m < Mvalid && n2 < Nvalid) {
                        float den = fmaxf(lrow[m], 1e-30f);
                        float r = v / den + ldf(bias, n2, f32);
                        vout[m * Nvalid + n2] = f2b(sane(fmaxf(r, 0.f)));
                    }
                }
            }
}

// ---------------- GEMM1 fallback: raw operands, dtype-dual scalar staging ----------------
__global__ __launch_bounds__(256)
void gemm1_raw(const void* __restrict__ A, const void* __restrict__ B, int K,
               int lda, int ldb, int Ma, int Nb, int Kv,
               __hip_bfloat16* __restrict__ Cbf, int ldc, const int* __restrict__ fdt)
{
    __shared__ __align__(16) ushort sA[128 * 64];
    __shared__ __align__(16) ushort sB[128 * 64];
    const int f32 = fdt[0];
    const int tid = threadIdx.x;
    const int lane = tid & 63;
    const int wid = tid >> 6;
    const int wm = (wid >> 1) * 64;
    const int wn = (wid & 1) * 64;
    const long m0 = (long)blockIdx.y * 128;
    const long n0 = (long)blockIdx.x * 128;

    f32x4 acc[4][4];
#pragma unroll
    for (int i = 0; i < 4; ++i)
#pragma unroll
        for (int j = 0; j < 4; ++j) acc[i][j] = (f32x4){0.f, 0.f, 0.f, 0.f};

    const int lr = tid >> 3;
    const int lc = (tid & 7) * 8;
    const int koff = (lane >> 4) * 8;
    const int rowf = lane & 15;

    for (int k0 = 0; k0 < K; k0 += 64) {
        __syncthreads();
#pragma unroll
        for (int it = 0; it < 4; ++it) {
            int r = it * 32 + lr;
            long gm = m0 + r, gn = n0 + r;
            ushort va[8], vb[8];
#pragma unroll
            for (int e = 0; e < 8; ++e) {
                int k = k0 + lc + e;
                bool kok = (k < Kv);
                float fa = (kok && gm < Ma) ? ldf(A, gm * (long)lda + k, f32) : 0.f;
                float fb = (kok && gn < Nb) ? ldf(B, gn * (long)ldb + k, f32) : 0.f;
                va[e] = __hip_bfloat16_raw(f2b(fa)).x;
                vb[e] = __hip_bfloat16_raw(f2b(fb)).x;
            }
#pragma unroll
            for (int e = 0; e < 8; ++e) { sA[r * 64 + lc + e] = va[e]; sB[r * 64 + lc + e] = vb[e]; }
        }
        __syncthreads();
#pragma unroll
        for (int ks = 0; ks < 64; ks += 32) {
            short8 af[4], bfr[4];
            int kb = ks + koff;
#pragma unroll
            for (int f = 0; f < 4; ++f) {
                af[f]  = *(const short8*)(&sA[(wm + f * 16 + rowf) * 64 + kb]);
                bfr[f] = *(const short8*)(&sB[(wn + f * 16 + rowf) * 64 + kb]);
            }
#pragma unroll
            for (int i = 0; i < 4; ++i)
#pragma unroll
                for (int j = 0; j < 4; ++j)
                    acc[i][j] = __builtin_amdgcn_mfma_f32_16x16x32_bf16(af[i], bfr[j], acc[i][j], 0, 0, 0);
        }
    }

    const int rq = (lane >> 4) * 4;
#pragma unroll
    for (int i = 0; i < 4; ++i)
#pragma unroll
        for (int j = 0; j < 4; ++j)
#pragma unroll
            for (int rg = 0; rg < 4; ++rg) {
                long m = m0 + wm + i * 16 + rq + rg;
                long n = n0 + wn + j * 16 + (lane & 15);
                Cbf[m * ldc + n] = f2b(acc[i][j][rg]);
            }
}

// ---------------- asrc/adst: parallel over (j, o-chunks), atomic accumulate ----------------
__global__ void srcdst2(const __hip_bfloat16* __restrict__ hT,
                        const void* __restrict__ a_src, const void* __restrict__ a_dst,
                        int Nv, int Nvp, float* __restrict__ asrc, float* __restrict__ adst,
                        const int* __restrict__ fdt)
{
    const int f32 = fdt[0];
    int j = blockIdx.x * 256 + threadIdx.x;
    if (j >= Nv) return;
    int o0 = blockIdx.y * 113;
    int o1 = min(OUTF, o0 + 113);
    float s1 = 0.f, s2 = 0.f;
    for (int o = o0; o < o1; ++o) {
        float hv = b2f(hT[(long)o * Nvp + j]);
        s1 += hv * ldf(a_src, o, f32);
        s2 += hv * ldf(a_dst, o, f32);
    }
    atomicAdd(&asrc[j], s1);
    atomicAdd(&adst[j], s2);
}

// ---------------- P = mask * exp(leaky(adst_i + asrc_j)), row sums l ----------------
// adj tile staged through LDS so global adj reads are coalesced along i.
__global__ void pbuild(const int* __restrict__ adj, const float* __restrict__ asrc,
                       const float* __restrict__ adst, int Nv, int Nvp, int ioff,
                       __hip_bfloat16* __restrict__ P, float* __restrict__ l)
{
    __shared__ int sAdj[64][65];
    const int lane = threadIdx.x & 63, grp = threadIdx.x >> 6;
    const int j0 = blockIdx.x * 64, r0 = blockIdx.y * 64;

    // Phase A: sAdj[jr][c] = adj[(j0+jr)*Nv + i(r0+c)], coalesced (lane = c)
    {
        int r_lane = r0 + lane;
        bool rv = (r_lane < NROWS);
        int i_lane = (r_lane < 901) ? r_lane : r_lane + ioff;   // < Nv when rv
#pragma unroll
        for (int it = 0; it < 16; ++it) {
            int jr = it * 4 + grp;
            int j = j0 + jr;
            int v = 0;
            if (j < Nv && rv) v = adj[(long)j * Nv + i_lane];
            sAdj[jr][lane] = v;
        }
    }
    __syncthreads();

    // Phase B: original compute, lane = j; mask from sAdj[lane][rr]
    const int j = j0 + lane;
    const float as = (j < Nv) ? asrc[j] : 0.f;
#pragma unroll
    for (int it = 0; it < 16; ++it) {
        int rr = it * 4 + grp;
        int r = r0 + rr;
        int i = (r < 901) ? r : r + ioff;
        float p = 0.f;
        if (r < NROWS && j < Nv) {
            bool m = (sAdj[lane][rr] != 0) || (i == j);
            if (m) {
                float e = adst[i] + as;
                e = e > 0.f ? e : 0.2f * e;
                p = expf(fminf(e, 30.f));
            }
        }
        __hip_bfloat16 pb = f2b(p);
        if (r < 1792) P[(long)r * Nvp + j] = pb;
        float pv = b2f(pb);
        for (int o = 32; o; o >>= 1) pv += __shfl_down(pv, o);
        if (lane == 0 && r < NROWS) atomicAdd(&l[r], pv);
    }
}

// ---------------- CAM (vectorized, zero-atomic two-stage reduction) ----------------
__device__ __forceinline__ void block_part4(float a, float b, float c, float d, float4* out)
{
    for (int o = 32; o; o >>= 1) {
        a += __shfl_down(a, o); b += __shfl_down(b, o);
        c += __shfl_down(c, o); d += __shfl_down(d, o);
    }
    __shared__ float s[4][4];
    int lane = threadIdx.x & 63, wv = threadIdx.x >> 6;
    if (lane == 0) { s[wv][0] = a; s[wv][1] = b; s[wv][2] = c; s[wv][3] = d; }
    __syncthreads();
    if (threadIdx.x == 0)
        *out = make_float4(s[0][0] + s[1][0] + s[2][0] + s[3][0],
                           s[0][1] + s[1][1] + s[2][1] + s[3][1],
                           s[0][2] + s[1][2] + s[2][2] + s[3][2],
                           s[0][3] + s[1][3] + s[2][3] + s[3][3]);
}

__device__ __forceinline__ void camY(int idx,
    const __hip_bfloat16* v0, const __hip_bfloat16* v1, const __hip_bfloat16* v2,
    const void* md, const void* lw1, const void* lb1, const void* gw1, const void* gb1,
    int f32, float& Yl, float& Yg)
{
    float x0 = b2f(v0[idx]), x1 = b2f(v1[idx]), x2 = b2f(v2[idx]), x3 = ldf(md, idx, f32);
    Yl = ldf(lw1,0,f32)*x0 + ldf(lw1,1,f32)*x1 + ldf(lw1,2,f32)*x2 + ldf(lw1,3,f32)*x3 + ldf(lb1,0,f32);
    Yg = ldf(gw1,0,f32)*x0 + ldf(gw1,1,f32)*x1 + ldf(gw1,2,f32)*x2 + ldf(gw1,3,f32)*x3 + ldf(gb1,0,f32);
}

// vector camY: 8 elements at base (base%8==0, base+8<=NEL)
__device__ __forceinline__ void camY8(long base,
    const __hip_bfloat16* v0, const __hip_bfloat16* v1, const __hip_bfloat16* v2,
    const void* md, const void* lw1, const void* lb1, const void* gw1, const void* gb1,
    int f32, float* Yl, float* Yg, float x[4][8])
{
    ld8b(v0, base, x[0]); ld8b(v1, base, x[1]); ld8b(v2, base, x[2]);
    ld8d(md, base, f32, x[3]);
    float wl0 = ldf(lw1,0,f32), wl1 = ldf(lw1,1,f32), wl2 = ldf(lw1,2,f32), wl3 = ldf(lw1,3,f32);
    float wg0 = ldf(gw1,0,f32), wg1 = ldf(gw1,1,f32), wg2 = ldf(gw1,2,f32), wg3 = ldf(gw1,3,f32);
    float bl = ldf(lb1,0,f32), bg = ldf(gb1,0,f32);
#pragma unroll
    for (int e = 0; e < 8; ++e) {
        Yl[e] = wl0*x[0][e] + wl1*x[1][e] + wl2*x[2][e] + wl3*x[3][e] + bl;
        Yg[e] = wg0*x[0][e] + wg1*x[1][e] + wg2*x[2][e] + wg3*x[3][e] + bg;
    }
}

__global__ void cam_pass1(const __hip_bfloat16* __restrict__ v0, const __hip_bfloat16* __restrict__ v1,
                          const __hip_bfloat16* __restrict__ v2, const void* __restrict__ md,
                          const void* __restrict__ lw1, const void* __restrict__ lb1,
                          const void* __restrict__ gw1, const void* __restrict__ gb1,
                          float4* __restrict__ part, const int* __restrict__ fdt)
{
    long base = ((long)blockIdx.x * 256 + threadIdx.x) * 8;
    float a = 0, b = 0, c = 0, d = 0;
    const int f32 = fdt[0];
    if (base + 8 <= NEL) {
        float Yl[8], Yg[8], x[4][8];
        camY8(base, v0, v1, v2, md, lw1, lb1, gw1, gb1, f32, Yl, Yg, x);
#pragma unroll
        for (int e = 0; e < 8; ++e) { a += Yl[e]; b += Yl[e]*Yl[e]; c += Yg[e]; d += Yg[e]*Yg[e]; }
    } else if (base < NEL) {
        for (long i = base; i < NEL; ++i) {
            float Yl, Yg;
            camY((int)i, v0, v1, v2, md, lw1, lb1, gw1, gb1, f32, Yl, Yg);
            a += Yl; b += Yl*Yl; c += Yg; d += Yg*Yg;
        }
    }
    block_part4(a, b, c, d, &part[blockIdx.x]);
}

__global__ void cam_fin1(const float4* __restrict__ part, float* __restrict__ sF)
{
    int t = threadIdx.x;
    double a = 0, b = 0, c = 0, d = 0;
    for (int i = t; i < CAMNB; i += 256) {
        float4 p = part[i];
        a += p.x; b += p.y; c += p.z; d += p.w;
    }
    for (int o = 32; o; o >>= 1) {
        a += __shfl_down(a, o); b += __shfl_down(b, o);
        c += __shfl_down(c, o); d += __shfl_down(d, o);
    }
    __shared__ double sd[4][4];
    int lane = t & 63, wv = t >> 6;
    if (!lane) { sd[wv][0] = a; sd[wv][1] = b; sd[wv][2] = c; sd[wv][3] = d; }
    __syncthreads();
    if (t == 0) {
        double n = (double)NEL;
        double A = sd[0][0]+sd[1][0]+sd[2][0]+sd[3][0];
        double B = sd[0][1]+sd[1][1]+sd[2][1]+sd[3][1];
        double C = sd[0][2]+sd[1][2]+sd[2][2]+sd[3][2];
        double D = sd[0][3]+sd[1][3]+sd[2][3]+sd[3][3];
        double ml = A / n, vl = B / n - ml * ml;
        double mg = C / n, vg = D / n - mg * mg;
        if (vl < 0.0) vl = 0.0;
        if (vg < 0.0) vg = 0.0;
        sF[0] = (float)ml; sF[1] = (float)(1.0 / sqrt(vl + 1e-5));
        sF[2] = (float)mg; sF[3] = (float)(1.0 / sqrt(vg + 1e-5));
    }
}

__global__ void cam_pass2(const __hip_bfloat16* __restrict__ v0, const __hip_bfloat16* __restrict__ v1,
                          const __hip_bfloat16* __restrict__ v2, const void* __restrict__ md,
                          const void* __restrict__ lw1, const void* __restrict__ lb1,
                          const void* __restrict__ gw1, const void* __restrict__ gb1,
                          const float* __restrict__ sF, float4* __restrict__ part,
                          const int* __restrict__ fdt)
{
    long base = ((long)blockIdx.x * 256 + threadIdx.x) * 8;
    float a = 0, b = 0, c = 0, d = 0;
    const int f32 = fdt[0];
    const float m_l = sF[0], is_l = sF[1], m_g = sF[2], is_g = sF[3];
    if (base + 8 <= NEL) {
        float Yl[8], Yg[8], x[4][8];
        camY8(base, v0, v1, v2, md, lw1, lb1, gw1, gb1, f32, Yl, Yg, x);
#pragma unroll
        for (int e = 0; e < 8; ++e) {
            float zl = fmaxf((Yl[e] - m_l) * is_l, 0.f);
            float zg = fmaxf((Yg[e] - m_g) * is_g, 0.f);
            a += zl; b += zl*zl; c += zg; d += zg*zg;
        }
    } else if (base < NEL) {
        for (long i = base; i < NEL; ++i) {
            float Yl, Yg;
            camY((int)i, v0, v1, v2, md, lw1, lb1, gw1, gb1, f32, Yl, Yg);
            float zl = fmaxf((Yl - m_l) * is_l, 0.f);
            float zg = fmaxf((Yg - m_g) * is_g, 0.f);
            a += zl; b += zl*zl; c += zg; d += zg*zg;
        }
    }
    block_part4(a, b, c, d, &part[blockIdx.x]);
}

__global__ void cam_fin2(const float4* __restrict__ part, float* __restrict__ sF,
                         const void* __restrict__ lw2, const void* __restrict__ gw2,
                         const int* __restrict__ fdt)
{
    int t = threadIdx.x;
    double a = 0, b = 0, c = 0, d = 0;
    for (int i = t; i < CAMNB; i += 256) {
        float4 p = part[i];
        a += p.x; b += p.y; c += p.z; d += p.w;
    }
    for (int o = 32; o; o >>= 1) {
        a += __shfl_down(a, o); b += __shfl_down(b, o);
        c += __shfl_down(c, o); d += __shfl_down(d, o);
    }
    __shared__ double sd[4][4];
    int lane = t & 63, wv = t >> 6;
    if (!lane) { sd[wv][0] = a; sd[wv][1] = b; sd[wv][2] = c; sd[wv][3] = d; }
    __syncthreads();
    if (t == 0) {
        const int f32 = fdt[0];
        double n = (double)NEL;
        double A = sd[0][0]+sd[1][0]+sd[2][0]+sd[3][0];
        double B = sd[0][1]+sd[1][1]+sd[2][1]+sd[3][1];
        double C = sd[0][2]+sd[1][2]+sd[2][2]+sd[3][2];
        double D = sd[0][3]+sd[1][3]+sd[2][3]+sd[3][3];
        double mzl = A / n, vzl = B / n - mzl * mzl;
        double mzg = C / n, vzg = D / n - mzg * mzg;
        if (vzl < 0.0) vzl = 0.0;
        if (vzg < 0.0) vzg = 0.0;
        sF[4] = (float)mzl; sF[5] = (float)mzg;
        for (int c2 = 0; c2 < 4; ++c2) {
            double wl = (double)ldf(lw2, c2, f32);
            double wg = (double)ldf(gw2, c2, f32);
            sF[6 + c2]  = (float)(wl / sqrt(wl * wl * vzl + 1e-5));
            sF[10 + c2] = (float)(wg / sqrt(wg * wg * vzg + 1e-5));
        }
    }
}

__global__ void cam_fuse(const __hip_bfloat16* __restrict__ v0, const __hip_bfloat16* __restrict__ v1,
                         const __hip_bfloat16* __restrict__ v2, const void* __restrict__ md,
                         const void* __restrict__ lw1, const void* __restrict__ lb1,
                         const void* __restrict__ gw1, const void* __restrict__ gb1,
                         const float* __restrict__ sF, float* __restrict__ sumx,
                         const int* __restrict__ fdt)
{
    long base = ((long)blockIdx.x * 256 + threadIdx.x) * 8;
    if (base >= NEL) return;
    const int f32 = fdt[0];
    const float m_l = sF[0], is_l = sF[1], m_g = sF[2], is_g = sF[3];
    const float mzl = sF[4], mzg = sF[5];
    float wl2[4], wg2[4];
#pragma unroll
    for (int c = 0; c < 4; ++c) { wl2[c] = sF[6 + c]; wg2[c] = sF[10 + c]; }

    if (base + 8 <= NEL) {
        float Yl[8], Yg[8], x[4][8], sv[8];
        camY8(base, v0, v1, v2, md, lw1, lb1, gw1, gb1, f32, Yl, Yg, x);
#pragma unroll
        for (int e = 0; e < 8; ++e) {
            float zl = fmaxf((Yl[e] - m_l) * is_l, 0.f);
            float zg = fmaxf((Yg[e] - m_g) * is_g, 0.f);
            float dzl = zl - mzl, dzg = zg - mzg;
            float s = 0.f;
#pragma unroll
            for (int c = 0; c < 4; ++c) {
                float t2 = wl2[c] * dzl + wg2[c] * dzg;
                s += x[c][e] / (1.f + expf(-t2));
            }
            sv[e] = 0.25f * s;
        }
        *(float4*)(sumx + base)     = make_float4(sv[0], sv[1], sv[2], sv[3]);
        *(float4*)(sumx + base + 4) = make_float4(sv[4], sv[5], sv[6], sv[7]);
    } else {
        for (long i = base; i < NEL; ++i) {
            float Yl, Yg;
            camY((int)i, v0, v1, v2, md, lw1, lb1, gw1, gb1, f32, Yl, Yg);
            float zl = fmaxf((Yl - m_l) * is_l, 0.f);
            float zg = fmaxf((Yg - m_g) * is_g, 0.f);
            float dzl = zl - mzl, dzg = zg - mzg;
            float xx[4] = {b2f(v0[i]), b2f(v1[i]), b2f(v2[i]), ldf(md, i, f32)};
            float s = 0.f;
#pragma unroll
            for (int c = 0; c < 4; ++c) {
                float t2 = wl2[c] * dzl + wg2[c] * dzg;
                s += xx[c] / (1.f + expf(-t2));
            }
            sumx[i] = 0.25f * s;
        }
    }
}

// ---------------- collapsed MLP head (parallel, multi-kernel) ----------------
__global__ void mlp_a(const void* __restrict__ mW3, const void* __restrict__ mW4,
                      const void* __restrict__ mb2, const void* __restrict__ mb3,
                      const void* __restrict__ mb4,
                      float* __restrict__ u3g, float* __restrict__ u2g,
                      float* __restrict__ sF, const int* __restrict__ fdt)
{
    __shared__ float u3[64];
    __shared__ float red[4];
    const int f32 = fdt[0];
    int t = threadIdx.x;
    if (t < 64) { float v = ldf(mW4, t, f32); u3[t] = v; u3g[t] = v; }
    __syncthreads();
    float part = 0.f;
    for (int k = t; k < 512; k += 256) {
        float s = 0.f;
#pragma unroll
        for (int o = 0; o < 64; ++o) s += ldf(mW3, o * 512 + k, f32) * u3[o];
        u2g[k] = s;
        part += ldf(mb2, k, f32) * s;
    }
    if (t < 64) part += ldf(mb3, t, f32) * u3[t];
    for (int o = 32; o; o >>= 1) part += __shfl_down(part, o);
    if ((t & 63) == 0) red[t >> 6] = part;
    __syncthreads();
    if (t == 0) sF[15] = red[0] + red[1] + red[2] + red[3] + ldf(mb4, 0, f32);
}

__global__ void mlp_b1(const void* __restrict__ mW2, const float* __restrict__ u2g,
                       float* __restrict__ part1, const int* __restrict__ fdt)
{
    int k = blockIdx.x * 256 + threadIdx.x;
    int o0 = blockIdx.y * 64;
    const int f32 = fdt[0];
    float s = 0.f;
#pragma unroll
    for (int oi = 0; oi < 64; ++oi) s += ldf(mW2, (long)(o0 + oi) * 1024 + k, f32) * u2g[o0 + oi];
    part1[blockIdx.y * 1024 + k] = s;
}

__global__ void mlp_b2(const float* __restrict__ part1, float* __restrict__ u1g)
{
    int k = blockIdx.x * 256 + threadIdx.x;
    float s = 0.f;
#pragma unroll
    for (int ob = 0; ob < 8; ++ob) s += part1[ob * 1024 + k];
    u1g[k] = s;
}

__global__ void mlp_c(const void* __restrict__ mb1, const float* __restrict__ u1g,
                      float* __restrict__ sF, const int* __restrict__ fdt)
{
    __shared__ float red[4];
    int t = threadIdx.x;
    const int f32 = fdt[0];
    float p = 0.f;
    for (int k = t; k < 1024; k += 256) p += ldf(mb1, k, f32) * u1g[k];
    for (int o = 32; o; o >>= 1) p += __shfl_down(p, o);
    if ((t & 63) == 0) red[t >> 6] = p;
    __syncthreads();
    if (t == 0) sF[14] = sF[15] + red[0] + red[1] + red[2] + red[3];
}

__global__ void mlp_u0s1(const void* __restrict__ mW1, const float* __restrict__ u1g,
                         float* __restrict__ part0, const int* __restrict__ fdt)
{
    int k = blockIdx.x * 256 + threadIdx.x;
    if (k >= 1802) return;
    int o0 = blockIdx.y * 64;
    const int f32 = fdt[0];
    float s = 0.f;
#pragma unroll
    for (int oi = 0; oi < 64; ++oi) s += ldf(mW1, (long)(o0 + oi) * 1802 + k, f32) * u1g[o0 + oi];
    part0[blockIdx.y * 2048 + k] = s;
}

__global__ void mlp_u0s2(const float* __restrict__ part0, float* __restrict__ u0)
{
    int k = blockIdx.x * 256 + threadIdx.x;
    if (k >= 1802) return;
    float s = 0.f;
#pragma unroll
    for (int ob = 0; ob < 16; ++ob) s += part0[ob * 2048 + k];
    u0[k] = s;
}

__global__ void rowdot(const float* __restrict__ sumx, const float* __restrict__ u0,
                       float* __restrict__ f, float* __restrict__ g)
{
    int r = blockIdx.x, t = threadIdx.x;
    float fa = 0.f, ga = 0.f;
    for (int o = t; o < OUTF; o += 256) {
        float v = sumx[(long)r * OUTF + o];
        fa += v * u0[o];
        ga += v * u0[OUTF + o];
    }
    for (int o = 32; o; o >>= 1) { fa += __shfl_down(fa, o); ga += __shfl_down(ga, o); }
    __shared__ float s[4][2];
    int lane = t & 63, wv = t >> 6;
    if (!lane) { s[wv][0] = fa; s[wv][1] = ga; }
    __syncthreads();
    if (t == 0) {
        f[r] = s[0][0] + s[1][0] + s[2][0] + s[3][0];
        g[r] = s[0][1] + s[1][1] + s[2][1] + s[3][1];
    }
}

__global__ void score(const int* __restrict__ ts, const float* __restrict__ f,
                      const float* __restrict__ g, const float* __restrict__ sF,
                      void* __restrict__ out, const int* __restrict__ fdt)
{
    int p = blockIdx.x * 256 + threadIdx.x;
    if (p >= 4096) return;
    float v = sane(f[ts[2 * p]] + g[ts[2 * p + 1]] + sF[14]);
    if (fdt[0]) ((float*)out)[p] = v;
    else        ((__hip_bfloat16*)out)[p] = f2b(v);
}

// ---------------- launch ----------------
extern "C" void kernel_launch(void* const* d_in, const int* in_sizes, int n_in,
                              void* d_out, int out_size, void* d_ws, size_t ws_size,
                              hipStream_t stream)
{
    const int NVv[3]   = {2060, 2459, 3929};
    const int NVPv[3]  = {2176, 2560, 3968};
    const int IOFFv[3] = {282, 681, 2151};
    const int ADJ_I[3] = {0, 1, 2}, FEAT_I[3] = {4, 5, 6}, W_I[3] = {8, 12, 16},
              AS_I[3] = {9, 13, 17}, AD_I[3] = {10, 14, 18}, BV_I[3] = {11, 15, 19};

    char* w = (char*)d_ws;
    size_t off = 0;
    auto alloc = [&](size_t b) { void* p = w + off; off += (b + 255) & ~(size_t)255; return p; };

    ushort* hT   = (ushort*)alloc(1024ULL * 3968 * 2);            // 8.1 MB
    ushort* Pexp = (ushort*)alloc(1792ULL * 3968 * 2);            // 14.2 MB
    __hip_bfloat16* voutb[3];
    for (int v = 0; v < 3; ++v)
        voutb[v] = (__hip_bfloat16*)alloc((size_t)NROWS * OUTF * 2);  // 3x 3.2 MB
    // asrc/adst/lrow contiguous (each size multiple of 256B) -> single zerof
    float*  asrc   = (float*)alloc(3968 * 4);
    float*  adst   = (float*)alloc(3968 * 4);
    float*  lrow   = (float*)alloc(1792 * 4);
    float*  statsF = (float*)alloc(16 * 4);
    float*  u3g    = (float*)alloc(64 * 4);
    float*  u2g    = (float*)alloc(512 * 4);
    float*  u1     = (float*)alloc(1024 * 4);
    float*  u0     = (float*)alloc(1802 * 4);
    float*  part1  = (float*)alloc(8 * 1024 * 4);
    float*  part0  = (float*)alloc(16 * 2048 * 4);
    float*  fv     = (float*)alloc(NROWS * 4);
    float*  gv     = (float*)alloc(NROWS * 4);
    int*    fdt    = (int*)alloc(4);
    float4* cp1    = (float4*)alloc(CAMNB * 16);
    float4* cp2    = (float4*)alloc(CAMNB * 16);
    // fast-path-only: featPad allocated last so the compact set fits small ws
    ushort* featPad = (ushort*)alloc(3968ULL * 3968 * 2);         // 31.5 MB
    const bool use_fast = (ws_size >= off);
    // overlays on dead regions
    ushort* Wpad = Pexp;            // Wpad (8.1 MB) lives in Pexp (14.2 MB) during gemm1
    float*  sumx = (float*)hT;      // hT dead after view loop; sumx 6.4 MB < 8.1 MB

    probe_dtype<<<1, 256, 0, stream>>>((const ushort*)d_in[9], fdt);

    for (int v = 0; v < 3; ++v) {
        int Nv = NVv[v], Nvp = NVPv[v], ioff2 = IOFFv[v];
        int Kp = (Nv + 63) & ~63;

        dim3 gg1(Nvp / 128, 8);   // hT[1024, Nvp] = W · feat^T
        if (use_fast) {
            dim3 gpk((Nvp + 255) / 256, Nvp);
            pack_dual<<<gpk, 256, 0, stream>>>((__hip_bfloat16*)featPad, d_in[FEAT_I[v]],
                                               Nv, Nv, Nv, Nvp, fdt);
            dim3 gpw((Nvp + 255) / 256, 1024);
            pack_dual<<<gpw, 256, 0, stream>>>((__hip_bfloat16*)Wpad, d_in[W_I[v]],
                                               901, Nv, Nv, Nvp, fdt);
            // B (featPad) is the big operand -> cluster same-x per XCD
            gemm_fast<0, 1><<<gg1, 512, 0, stream>>>(Wpad, featPad, Nvp,
                (__hip_bfloat16*)hT, Nvp, nullptr, nullptr, nullptr, 0, 0, fdt);
        } else {
            gemm1_raw<<<gg1, 256, 0, stream>>>(d_in[W_I[v]], d_in[FEAT_I[v]], Kp,
                                               Nv, Nv, 901, Nv, Nv,
                                               (__hip_bfloat16*)hT, Nvp, fdt);
        }

        // zero asrc+adst+lrow in one shot (contiguous: 3968+3968+1792 floats)
        zerof<<<38, 256, 0, stream>>>(asrc, 3968 + 3968 + 1792);

        dim3 gsd((Nv + 255) / 256, 8);
        srcdst2<<<gsd, 256, 0, stream>>>((const __hip_bfloat16*)hT,
            d_in[AS_I[v]], d_in[AD_I[v]], Nv, Nvp, asrc, adst, fdt);

        dim3 gp(Nvp / 64, 28);
        pbuild<<<gp, 256, 0, stream>>>((const int*)d_in[ADJ_I[v]], asrc, adst, Nv, Nvp, ioff2,
                                       (__hip_bfloat16*)Pexp, lrow);

        dim3 gg2(8, 14);          // vout[1778,901] = relu(P·h / l + b)
        // A (Pexp) is the big operand -> cluster same-y per XCD
        gemm_fast<1, 0><<<gg2, 512, 0, stream>>>(Pexp, hT, Nvp,
            nullptr, 0, lrow, d_in[BV_I[v]], voutb[v], NROWS, OUTF, fdt);
    }

    cam_pass1<<<CAMNB, 256, 0, stream>>>(voutb[0], voutb[1], voutb[2], d_in[7],
        d_in[20], d_in[21], d_in[24], d_in[25], cp1, fdt);
    cam_fin1<<<1, 256, 0, stream>>>(cp1, statsF);
    cam_pass2<<<CAMNB, 256, 0, stream>>>(voutb[0], voutb[1], voutb[2], d_in[7],
        d_in[20], d_in[21], d_in[24], d_in[25], statsF, cp2, fdt);
    cam_fin2<<<1, 256, 0, stream>>>(cp2, statsF, d_in[22], d_in[26], fdt);
    cam_fuse<<<CAMNB, 256, 0, stream>>>(voutb[0], voutb[1], voutb[2], d_in[7],
        d_in[20], d_in[21], d_in[24], d_in[25], statsF, sumx, fdt);

    // collapsed MLP head, parallelized
    mlp_a<<<1, 256, 0, stream>>>(d_in[32], d_in[34], d_in[31], d_in[33], d_in[35],
                                 u3g, u2g, statsF, fdt);
    mlp_b1<<<dim3(4, 8), 256, 0, stream>>>(d_in[30], u2g, part1, fdt);
    mlp_b2<<<4, 256, 0, stream>>>(part1, u1);
    mlp_c<<<1, 256, 0, stream>>>(d_in[29], u1, statsF, fdt);
    mlp_u0s1<<<dim3(8, 16), 256, 0, stream>>>(d_in[28], u1, part0, fdt);
    mlp_u0s2<<<8, 256, 0, stream>>>(part0, u0);

    rowdot<<<NROWS, 256, 0, stream>>>(sumx, u0, fv, gv);
    score<<<16, 256, 0, stream>>>((const int*)d_in[3], fv, gv, statsF, d_out, fdt);
}

// Round 6
// 809.401 us; speedup vs baseline: 1.1130x; 1.0095x over previous
//
#include <hip/hip_runtime.h>
#include <hip/hip_bf16.h>
#include <stdint.h>

typedef __attribute__((ext_vector_type(8))) short short8;
typedef __attribute__((ext_vector_type(4))) float f32x4;

#define AS1 __attribute__((address_space(1)))
#define AS3 __attribute__((address_space(3)))

#define NEL 1601978   // 1778*901
#define NROWS 1778
#define OUTF 901
#define CAMNB 783     // ceil(NEL / (256*8))

__device__ __forceinline__ float b2f(__hip_bfloat16 x) { return __bfloat162float(x); }
__device__ __forceinline__ __hip_bfloat16 f2b(float x) { return __float2bfloat16(x); }
__device__ __forceinline__ float sane(float v) { return isfinite(v) ? v : 0.f; }

// dtype-dual load: flag==1 -> fp32 array, flag==0 -> bf16 array
__device__ __forceinline__ float ldf(const void* p, long i, int f32)
{
    return f32 ? ((const float*)p)[i] : b2f(((const __hip_bfloat16*)p)[i]);
}

// 8-wide vector loads (base must be 8-aligned in elements)
__device__ __forceinline__ void ld8b(const __hip_bfloat16* p, long base, float* out)
{
    short8 t = *(const short8*)(p + base);
#pragma unroll
    for (int e = 0; e < 8; ++e) out[e] = __uint_as_float(((uint)(ushort)t[e]) << 16);
}
__device__ __forceinline__ void ld8d(const void* p, long base, int f32, float* out)
{
    if (f32) {
        const float4* q = (const float4*)((const float*)p + base);
        float4 a = q[0], b = q[1];
        out[0]=a.x; out[1]=a.y; out[2]=a.z; out[3]=a.w;
        out[4]=b.x; out[5]=b.y; out[6]=b.z; out[7]=b.w;
    } else {
        short8 t = *(const short8*)((const __hip_bfloat16*)p + base);
#pragma unroll
        for (int e = 0; e < 8; ++e) out[e] = __uint_as_float(((uint)(ushort)t[e]) << 16);
    }
}

// ---------------- dtype probe ----------------
__global__ void probe_dtype(const ushort* __restrict__ p, int* __restrict__ fdt)
{
    int t = threadIdx.x;
    int cnt = 0;
    for (int i = t; i < 512; i += 256) {
        int ex = (p[i] >> 7) & 0xFF;
        if (ex >= 0x85) cnt++;
    }
    for (int o = 32; o; o >>= 1) cnt += __shfl_down(cnt, o);
    __shared__ int s[4];
    if ((t & 63) == 0) s[t >> 6] = cnt;
    __syncthreads();
    if (t == 0) fdt[0] = (s[0] + s[1] + s[2] + s[3] > 16) ? 1 : 0;
}

// ---------------- zero scratch ----------------
__global__ void zerof(float* __restrict__ p, int n)
{
    int i = blockIdx.x * 256 + threadIdx.x;
    if (i < n) p[i] = 0.f;
}

// ---------------- pack (fp32|bf16) -> padded bf16, 8 elems/thread ----------------
// G13: vectorized short8 store (16B); 8 batched loads/thread for ILP.
// dst_ld % 8 == 0 (2176/2560/3968), so stores are 16B-aligned.
__global__ void pack_dual(__hip_bfloat16* __restrict__ dst, const void* __restrict__ src,
                          int rows_valid, int cols_valid, int src_ld, int dst_ld,
                          const int* __restrict__ fdt)
{
    int c0 = (blockIdx.x * 256 + threadIdx.x) * 8;
    int r = blockIdx.y;
    if (c0 >= dst_ld) return;
    const int f32 = fdt[0];
    short8 out;
    if (r < rows_valid) {
        long base = (long)r * src_ld;
#pragma unroll
        for (int e = 0; e < 8; ++e) {
            int c = c0 + e;
            float v = (c < cols_valid) ? ldf(src, base + c, f32) : 0.f;
            out[e] = (short)__hip_bfloat16_raw(f2b(v)).x;
        }
    } else {
#pragma unroll
        for (int e = 0; e < 8; ++e) out[e] = 0;
    }
    *(short8*)(dst + (long)r * dst_ld + c0) = out;
}

// ---------------- vector-staged bf16 GEMM: C = A(M,K) * B(N,K)^T ----------------
// BK=128, 2-buffer stage-before-compute schedule (round-5, proven).
// T2 swizzle: storage[r][c] = logical[r][c^(r&15)] via pre-swizzled global src.
// T1 XCD swizzle. See round-5 notes. Unchanged this round.
template<int EPI, int XMAJ>
__global__ __launch_bounds__(512)
void gemm_fast(const ushort* __restrict__ A, const ushort* __restrict__ B, int K,
               __hip_bfloat16* __restrict__ Cbf, int ldc,
               const float* __restrict__ lrow, const void* __restrict__ bias,
               __hip_bfloat16* __restrict__ vout, int Mvalid, int Nvalid,
               const int* __restrict__ fdt)
{
    __shared__ __align__(16) ushort sA[2][128 * 128];
    __shared__ __align__(16) ushort sB[2][128 * 128];
    const int tid = threadIdx.x;
    const int lane = tid & 63;
    const int wid = tid >> 6;          // 0..7
    const int wm = (wid >> 2) * 64;    // 2 wave rows (M)
    const int wn = (wid & 3) * 32;     // 4 wave cols (N)

    const int gx = gridDim.x, gy = gridDim.y;
    int lid = blockIdx.y * gx + blockIdx.x;
    int bx, by;
    const int n = gx * gy;
    if ((n & 7) == 0) {
        int q = n >> 3;
        int pos = (lid & 7) * q + (lid >> 3);
        if (XMAJ) { bx = pos / gy; by = pos - bx * gy; }
        else      { by = pos / gx; bx = pos - by * gx; }
    } else {
        bx = blockIdx.x; by = blockIdx.y;
    }
    const long m0 = (long)by * 128;
    const long n0 = (long)bx * 128;

    f32x4 acc[4][2];
#pragma unroll
    for (int i = 0; i < 4; ++i)
#pragma unroll
        for (int j = 0; j < 2; ++j) acc[i][j] = (f32x4){0.f, 0.f, 0.f, 0.f};

    const int rsub = lane >> 4;       // 0..3 row within 4-row slab
    const int cl   = lane & 15;       // 16B chunk slot within 256B row
    const int csub = cl * 8;          // LDS chunk offset (lane-linear, required)
    const int kgrp = lane >> 4;       // 0..3 k-chunk group of this lane's frag
    const int rowf = lane & 15;       // fragment row within 16

    auto stage = [&](int buf, int k0) {
#pragma unroll
        for (int it = 0; it < 4; ++it) {
            int rr = it * 4 + rsub;            // 0..15 == r & 15
            int r  = wid * 16 + rr;            // 8 waves x 16 rows = 128
            int gc = (cl ^ rr) * 8;            // pre-swizzled global chunk
            __builtin_amdgcn_global_load_lds(
                (const AS1 uint*)(const void*)(A + (m0 + r) * (long)K + k0 + gc),
                (AS3 uint*)&sA[buf][r * 128 + csub], 16, 0, 0);
            __builtin_amdgcn_global_load_lds(
                (const AS1 uint*)(const void*)(B + (n0 + r) * (long)K + k0 + gc),
                (AS3 uint*)&sB[buf][r * 128 + csub], 16, 0, 0);
        }
    };

    stage(0, 0);
    __syncthreads();                   // cold-start drain, once

    int cur = 0;
    for (int k0 = 0; k0 < K; k0 += 128) {
        if (k0 + 128 < K) stage(cur ^ 1, k0 + 128);   // prefetch next tile first
#pragma unroll
        for (int ks = 0; ks < 128; ks += 32) {
            short8 af[4], bfr[2];
            const int kc = (ks >> 3) + kgrp;        // logical 16B chunk 0..15
            const int kb = ((kc ^ rowf) << 3);      // swizzled storage offset
#pragma unroll
            for (int f = 0; f < 4; ++f)
                af[f]  = *(const short8*)(&sA[cur][(wm + f * 16 + rowf) * 128 + kb]);
#pragma unroll
            for (int f = 0; f < 2; ++f)
                bfr[f] = *(const short8*)(&sB[cur][(wn + f * 16 + rowf) * 128 + kb]);
#pragma unroll
            for (int i = 0; i < 4; ++i)
#pragma unroll
                for (int j = 0; j < 2; ++j)
                    acc[i][j] = __builtin_amdgcn_mfma_f32_16x16x32_bf16(af[i], bfr[j], acc[i][j], 0, 0, 0);
        }
        __syncthreads();   // drains vmcnt(0) (prefetch done) + lgkmcnt(0) (reads done)
        cur ^= 1;
    }

    const int f32 = (EPI == 1) ? fdt[0] : 0;
    const int rq = (lane >> 4) * 4;   // C/D: col = lane&15, row = (lane>>4)*4 + reg
#pragma unroll
    for (int i = 0; i < 4; ++i)
#pragma unroll
        for (int j = 0; j < 2; ++j)
#pragma unroll
            for (int rg = 0; rg < 4; ++rg) {
                long m = m0 + wm + i * 16 + rq + rg;
                long n2 = n0 + wn + j * 16 + (lane & 15);
                float v = acc[i][j][rg];
                if constexpr (EPI == 0) {
                    Cbf[m * ldc + n2] = f2b(v);
                } else {
                    if (m < Mvalid && n2 < Nvalid) {
                        float den = fmaxf(lrow[m], 1e-30f);
                        float r = v / den + ldf(bias, n2, f32);
                        vout[m * Nvalid + n2] = f2b(sane(fmaxf(r, 0.f)));
                    }
                }
            }
}

// ---------------- GEMM1 fallback: raw operands, dtype-dual scalar staging ----------------
__global__ __launch_bounds__(256)
void gemm1_raw(const void* __restrict__ A, const void* __restrict__ B, int K,
               int lda, int ldb, int Ma, int Nb, int Kv,
               __hip_bfloat16* __restrict__ Cbf, int ldc, const int* __restrict__ fdt)
{
    __shared__ __align__(16) ushort sA[128 * 64];
    __shared__ __align__(16) ushort sB[128 * 64];
    const int f32 = fdt[0];
    const int tid = threadIdx.x;
    const int lane = tid & 63;
    const int wid = tid >> 6;
    const int wm = (wid >> 1) * 64;
    const int wn = (wid & 1) * 64;
    const long m0 = (long)blockIdx.y * 128;
    const long n0 = (long)blockIdx.x * 128;

    f32x4 acc[4][4];
#pragma unroll
    for (int i = 0; i < 4; ++i)
#pragma unroll
        for (int j = 0; j < 4; ++j) acc[i][j] = (f32x4){0.f, 0.f, 0.f, 0.f};

    const int lr = tid >> 3;
    const int lc = (tid & 7) * 8;
    const int koff = (lane >> 4) * 8;
    const int rowf = lane & 15;

    for (int k0 = 0; k0 < K; k0 += 64) {
        __syncthreads();
#pragma unroll
        for (int it = 0; it < 4; ++it) {
            int r = it * 32 + lr;
            long gm = m0 + r, gn = n0 + r;
            ushort va[8], vb[8];
#pragma unroll
            for (int e = 0; e < 8; ++e) {
                int k = k0 + lc + e;
                bool kok = (k < Kv);
                float fa = (kok && gm < Ma) ? ldf(A, gm * (long)lda + k, f32) : 0.f;
                float fb = (kok && gn < Nb) ? ldf(B, gn * (long)ldb + k, f32) : 0.f;
                va[e] = __hip_bfloat16_raw(f2b(fa)).x;
                vb[e] = __hip_bfloat16_raw(f2b(fb)).x;
            }
#pragma unroll
            for (int e = 0; e < 8; ++e) { sA[r * 64 + lc + e] = va[e]; sB[r * 64 + lc + e] = vb[e]; }
        }
        __syncthreads();
#pragma unroll
        for (int ks = 0; ks < 64; ks += 32) {
            short8 af[4], bfr[4];
            int kb = ks + koff;
#pragma unroll
            for (int f = 0; f < 4; ++f) {
                af[f]  = *(const short8*)(&sA[(wm + f * 16 + rowf) * 64 + kb]);
                bfr[f] = *(const short8*)(&sB[(wn + f * 16 + rowf) * 64 + kb]);
            }
#pragma unroll
            for (int i = 0; i < 4; ++i)
#pragma unroll
                for (int j = 0; j < 4; ++j)
                    acc[i][j] = __builtin_amdgcn_mfma_f32_16x16x32_bf16(af[i], bfr[j], acc[i][j], 0, 0, 0);
        }
    }

    const int rq = (lane >> 4) * 4;
#pragma unroll
    for (int i = 0; i < 4; ++i)
#pragma unroll
        for (int j = 0; j < 4; ++j)
#pragma unroll
            for (int rg = 0; rg < 4; ++rg) {
                long m = m0 + wm + i * 16 + rq + rg;
                long n = n0 + wn + j * 16 + (lane & 15);
                Cbf[m * ldc + n] = f2b(acc[i][j][rg]);
            }
}

// ---------------- asrc/adst: parallel over (j, o-chunks), atomic accumulate ----------------
__global__ void srcdst2(const __hip_bfloat16* __restrict__ hT,
                        const void* __restrict__ a_src, const void* __restrict__ a_dst,
                        int Nv, int Nvp, float* __restrict__ asrc, float* __restrict__ adst,
                        const int* __restrict__ fdt)
{
    const int f32 = fdt[0];
    int j = blockIdx.x * 256 + threadIdx.x;
    if (j >= Nv) return;
    int o0 = blockIdx.y * 113;
    int o1 = min(OUTF, o0 + 113);
    float s1 = 0.f, s2 = 0.f;
    for (int o = o0; o < o1; ++o) {
        float hv = b2f(hT[(long)o * Nvp + j]);
        s1 += hv * ldf(a_src, o, f32);
        s2 += hv * ldf(a_dst, o, f32);
    }
    atomicAdd(&asrc[j], s1);
    atomicAdd(&adst[j], s2);
}

// ---------------- P = mask * exp(leaky(adst_i + asrc_j)), row sums l ----------------
// Restructured (round-6): the old per-row 6-deep __shfl_down chains (96 serial
// ds_bpermute per wave, VGPR=16 so zero ILP) dominated at 57us with all pipes
// idle. Now the row-sum is LANE-LOCAL: lane = r, each wave accumulates its 16
// j-columns in a register (no shuffles), staging bf16-rounded p in LDS; then a
// 4-partial LDS fold + 1 atomic/row, and a coalesced lane=j pass writes P from
// LDS. P bits and summed values identical to before (only f32 sum order moves).
__global__ void pbuild(const int* __restrict__ adj, const float* __restrict__ asrc,
                       const float* __restrict__ adst, int Nv, int Nvp, int ioff,
                       __hip_bfloat16* __restrict__ P, float* __restrict__ l)
{
    __shared__ int   sAdj[64][65];   // [j-local][r-local]
    __shared__ float sP[64][65];     // [r-local][j-local], bf16-rounded p
    __shared__ float sAs[64];
    __shared__ float sL[4][64];
    const int tid = threadIdx.x;
    const int lane = tid & 63, grp = tid >> 6;
    const int j0 = blockIdx.x * 64, r0 = blockIdx.y * 64;

    // per-lane row constants (lane = r-local in phases B/C)
    const int r = r0 + lane;
    const bool rv = (r < NROWS);
    const int i = (r < 901) ? r : r + ioff;   // source node index (valid when rv)

    // Phase A: stage adj^T tile (coalesced along i) + asrc tile
    if (tid < 64) sAs[tid] = (j0 + tid < Nv) ? asrc[j0 + tid] : 0.f;
#pragma unroll
    for (int it = 0; it < 16; ++it) {
        int jr = it * 4 + grp;
        int j = j0 + jr;
        int v = 0;
        if (j < Nv && rv) v = adj[(long)j * Nv + i];
        sAdj[jr][lane] = v;
    }
    const float adstv = rv ? adst[i] : 0.f;
    __syncthreads();

    // Phase B: lane = r; wave grp handles j-locals [grp*16, grp*16+16)
    float lsum = 0.f;
#pragma unroll
    for (int jj = 0; jj < 16; ++jj) {
        int jl = grp * 16 + jj;
        int j = j0 + jl;
        float p = 0.f;
        if (rv && j < Nv) {
            bool m = (sAdj[jl][lane] != 0) || (i == j);
            if (m) {
                float e = adstv + sAs[jl];
                e = e > 0.f ? e : 0.2f * e;
                p = expf(fminf(e, 30.f));
            }
        }
        float pr = b2f(f2b(p));     // bf16-rounded, matches previous arithmetic
        sP[lane][jl] = pr;
        lsum += pr;
    }
    sL[grp][lane] = lsum;
    __syncthreads();

    // Phase C: wave 0 folds the 4 per-wave partials, one atomic per row
    if (grp == 0 && rv) {
        float t = sL[0][lane] + sL[1][lane] + sL[2][lane] + sL[3][lane];
        atomicAdd(&l[r], t);
    }

    // Phase D: coalesced P write, lane = j (all rows in grid are < 1792)
#pragma unroll
    for (int it = 0; it < 16; ++it) {
        int rr = it * 4 + grp;
        P[(long)(r0 + rr) * Nvp + (j0 + lane)] = f2b(sP[rr][lane]);
    }
}

// ---------------- CAM (vectorized, zero-atomic two-stage reduction) ----------------
__device__ __forceinline__ void block_part4(float a, float b, float c, float d, float4* out)
{
    for (int o = 32; o; o >>= 1) {
        a += __shfl_down(a, o); b += __shfl_down(b, o);
        c += __shfl_down(c, o); d += __shfl_down(d, o);
    }
    __shared__ float s[4][4];
    int lane = threadIdx.x & 63, wv = threadIdx.x >> 6;
    if (lane == 0) { s[wv][0] = a; s[wv][1] = b; s[wv][2] = c; s[wv][3] = d; }
    __syncthreads();
    if (threadIdx.x == 0)
        *out = make_float4(s[0][0] + s[1][0] + s[2][0] + s[3][0],
                           s[0][1] + s[1][1] + s[2][1] + s[3][1],
                           s[0][2] + s[1][2] + s[2][2] + s[3][2],
                           s[0][3] + s[1][3] + s[2][3] + s[3][3]);
}

__device__ __forceinline__ void camY(int idx,
    const __hip_bfloat16* v0, const __hip_bfloat16* v1, const __hip_bfloat16* v2,
    const void* md, const void* lw1, const void* lb1, const void* gw1, const void* gb1,
    int f32, float& Yl, float& Yg)
{
    float x0 = b2f(v0[idx]), x1 = b2f(v1[idx]), x2 = b2f(v2[idx]), x3 = ldf(md, idx, f32);
    Yl = ldf(lw1,0,f32)*x0 + ldf(lw1,1,f32)*x1 + ldf(lw1,2,f32)*x2 + ldf(lw1,3,f32)*x3 + ldf(lb1,0,f32);
    Yg = ldf(gw1,0,f32)*x0 + ldf(gw1,1,f32)*x1 + ldf(gw1,2,f32)*x2 + ldf(gw1,3,f32)*x3 + ldf(gb1,0,f32);
}

// vector camY: 8 elements at base (base%8==0, base+8<=NEL)
__device__ __forceinline__ void camY8(long base,
    const __hip_bfloat16* v0, const __hip_bfloat16* v1, const __hip_bfloat16* v2,
    const void* md, const void* lw1, const void* lb1, const void* gw1, const void* gb1,
    int f32, float* Yl, float* Yg, float x[4][8])
{
    ld8b(v0, base, x[0]); ld8b(v1, base, x[1]); ld8b(v2, base, x[2]);
    ld8d(md, base, f32, x[3]);
    float wl0 = ldf(lw1,0,f32), wl1 = ldf(lw1,1,f32), wl2 = ldf(lw1,2,f32), wl3 = ldf(lw1,3,f32);
    float wg0 = ldf(gw1,0,f32), wg1 = ldf(gw1,1,f32), wg2 = ldf(gw1,2,f32), wg3 = ldf(gw1,3,f32);
    float bl = ldf(lb1,0,f32), bg = ldf(gb1,0,f32);
#pragma unroll
    for (int e = 0; e < 8; ++e) {
        Yl[e] = wl0*x[0][e] + wl1*x[1][e] + wl2*x[2][e] + wl3*x[3][e] + bl;
        Yg[e] = wg0*x[0][e] + wg1*x[1][e] + wg2*x[2][e] + wg3*x[3][e] + bg;
    }
}

__global__ void cam_pass1(const __hip_bfloat16* __restrict__ v0, const __hip_bfloat16* __restrict__ v1,
                          const __hip_bfloat16* __restrict__ v2, const void* __restrict__ md,
                          const void* __restrict__ lw1, const void* __restrict__ lb1,
                          const void* __restrict__ gw1, const void* __restrict__ gb1,
                          float4* __restrict__ part, const int* __restrict__ fdt)
{
    long base = ((long)blockIdx.x * 256 + threadIdx.x) * 8;
    float a = 0, b = 0, c = 0, d = 0;
    const int f32 = fdt[0];
    if (base + 8 <= NEL) {
        float Yl[8], Yg[8], x[4][8];
        camY8(base, v0, v1, v2, md, lw1, lb1, gw1, gb1, f32, Yl, Yg, x);
#pragma unroll
        for (int e = 0; e < 8; ++e) { a += Yl[e]; b += Yl[e]*Yl[e]; c += Yg[e]; d += Yg[e]*Yg[e]; }
    } else if (base < NEL) {
        for (long i = base; i < NEL; ++i) {
            float Yl, Yg;
            camY((int)i, v0, v1, v2, md, lw1, lb1, gw1, gb1, f32, Yl, Yg);
            a += Yl; b += Yl*Yl; c += Yg; d += Yg*Yg;
        }
    }
    block_part4(a, b, c, d, &part[blockIdx.x]);
}

__global__ void cam_fin1(const float4* __restrict__ part, float* __restrict__ sF)
{
    int t = threadIdx.x;
    double a = 0, b = 0, c = 0, d = 0;
    for (int i = t; i < CAMNB; i += 256) {
        float4 p = part[i];
        a += p.x; b += p.y; c += p.z; d += p.w;
    }
    for (int o = 32; o; o >>= 1) {
        a += __shfl_down(a, o); b += __shfl_down(b, o);
        c += __shfl_down(c, o); d += __shfl_down(d, o);
    }
    __shared__ double sd[4][4];
    int lane = t & 63, wv = t >> 6;
    if (!lane) { sd[wv][0] = a; sd[wv][1] = b; sd[wv][2] = c; sd[wv][3] = d; }
    __syncthreads();
    if (t == 0) {
        double n = (double)NEL;
        double A = sd[0][0]+sd[1][0]+sd[2][0]+sd[3][0];
        double B = sd[0][1]+sd[1][1]+sd[2][1]+sd[3][1];
        double C = sd[0][2]+sd[1][2]+sd[2][2]+sd[3][2];
        double D = sd[0][3]+sd[1][3]+sd[2][3]+sd[3][3];
        double ml = A / n, vl = B / n - ml * ml;
        double mg = C / n, vg = D / n - mg * mg;
        if (vl < 0.0) vl = 0.0;
        if (vg < 0.0) vg = 0.0;
        sF[0] = (float)ml; sF[1] = (float)(1.0 / sqrt(vl + 1e-5));
        sF[2] = (float)mg; sF[3] = (float)(1.0 / sqrt(vg + 1e-5));
    }
}

__global__ void cam_pass2(const __hip_bfloat16* __restrict__ v0, const __hip_bfloat16* __restrict__ v1,
                          const __hip_bfloat16* __restrict__ v2, const void* __restrict__ md,
                          const void* __restrict__ lw1, const void* __restrict__ lb1,
                          const void* __restrict__ gw1, const void* __restrict__ gb1,
                          const float* __restrict__ sF, float4* __restrict__ part,
                          const int* __restrict__ fdt)
{
    long base = ((long)blockIdx.x * 256 + threadIdx.x) * 8;
    float a = 0, b = 0, c = 0, d = 0;
    const int f32 = fdt[0];
    const float m_l = sF[0], is_l = sF[1], m_g = sF[2], is_g = sF[3];
    if (base + 8 <= NEL) {
        float Yl[8], Yg[8], x[4][8];
        camY8(base, v0, v1, v2, md, lw1, lb1, gw1, gb1, f32, Yl, Yg, x);
#pragma unroll
        for (int e = 0; e < 8; ++e) {
            float zl = fmaxf((Yl[e] - m_l) * is_l, 0.f);
            float zg = fmaxf((Yg[e] - m_g) * is_g, 0.f);
            a += zl; b += zl*zl; c += zg; d += zg*zg;
        }
    } else if (base < NEL) {
        for (long i = base; i < NEL; ++i) {
            float Yl, Yg;
            camY((int)i, v0, v1, v2, md, lw1, lb1, gw1, gb1, f32, Yl, Yg);
            float zl = fmaxf((Yl - m_l) * is_l, 0.f);
            float zg = fmaxf((Yg - m_g) * is_g, 0.f);
            a += zl; b += zl*zl; c += zg; d += zg*zg;
        }
    }
    block_part4(a, b, c, d, &part[blockIdx.x]);
}

__global__ void cam_fin2(const float4* __restrict__ part, float* __restrict__ sF,
                         const void* __restrict__ lw2, const void* __restrict__ gw2,
                         const int* __restrict__ fdt)
{
    int t = threadIdx.x;
    double a = 0, b = 0, c = 0, d = 0;
    for (int i = t; i < CAMNB; i += 256) {
        float4 p = part[i];
        a += p.x; b += p.y; c += p.z; d += p.w;
    }
    for (int o = 32; o; o >>= 1) {
        a += __shfl_down(a, o); b += __shfl_down(b, o);
        c += __shfl_down(c, o); d += __shfl_down(d, o);
    }
    __shared__ double sd[4][4];
    int lane = t & 63, wv = t >> 6;
    if (!lane) { sd[wv][0] = a; sd[wv][1] = b; sd[wv][2] = c; sd[wv][3] = d; }
    __syncthreads();
    if (t == 0) {
        const int f32 = fdt[0];
        double n = (double)NEL;
        double A = sd[0][0]+sd[1][0]+sd[2][0]+sd[3][0];
        double B = sd[0][1]+sd[1][1]+sd[2][1]+sd[3][1];
        double C = sd[0][2]+sd[1][2]+sd[2][2]+sd[3][2];
        double D = sd[0][3]+sd[1][3]+sd[2][3]+sd[3][3];
        double mzl = A / n, vzl = B / n - mzl * mzl;
        double mzg = C / n, vzg = D / n - mzg * mzg;
        if (vzl < 0.0) vzl = 0.0;
        if (vzg < 0.0) vzg = 0.0;
        sF[4] = (float)mzl; sF[5] = (float)mzg;
        for (int c2 = 0; c2 < 4; ++c2) {
            double wl = (double)ldf(lw2, c2, f32);
            double wg = (double)ldf(gw2, c2, f32);
            sF[6 + c2]  = (float)(wl / sqrt(wl * wl * vzl + 1e-5));
            sF[10 + c2] = (float)(wg / sqrt(wg * wg * vzg + 1e-5));
        }
    }
}

__global__ void cam_fuse(const __hip_bfloat16* __restrict__ v0, const __hip_bfloat16* __restrict__ v1,
                         const __hip_bfloat16* __restrict__ v2, const void* __restrict__ md,
                         const void* __restrict__ lw1, const void* __restrict__ lb1,
                         const void* __restrict__ gw1, const void* __restrict__ gb1,
                         const float* __restrict__ sF, float* __restrict__ sumx,
                         const int* __restrict__ fdt)
{
    long base = ((long)blockIdx.x * 256 + threadIdx.x) * 8;
    if (base >= NEL) return;
    const int f32 = fdt[0];
    const float m_l = sF[0], is_l = sF[1], m_g = sF[2], is_g = sF[3];
    const float mzl = sF[4], mzg = sF[5];
    float wl2[4], wg2[4];
#pragma unroll
    for (int c = 0; c < 4; ++c) { wl2[c] = sF[6 + c]; wg2[c] = sF[10 + c]; }

    if (base + 8 <= NEL) {
        float Yl[8], Yg[8], x[4][8], sv[8];
        camY8(base, v0, v1, v2, md, lw1, lb1, gw1, gb1, f32, Yl, Yg, x);
#pragma unroll
        for (int e = 0; e < 8; ++e) {
            float zl = fmaxf((Yl[e] - m_l) * is_l, 0.f);
            float zg = fmaxf((Yg[e] - m_g) * is_g, 0.f);
            float dzl = zl - mzl, dzg = zg - mzg;
            float s = 0.f;
#pragma unroll
            for (int c = 0; c < 4; ++c) {
                float t2 = wl2[c] * dzl + wg2[c] * dzg;
                s += x[c][e] / (1.f + expf(-t2));
            }
            sv[e] = 0.25f * s;
        }
        *(float4*)(sumx + base)     = make_float4(sv[0], sv[1], sv[2], sv[3]);
        *(float4*)(sumx + base + 4) = make_float4(sv[4], sv[5], sv[6], sv[7]);
    } else {
        for (long i = base; i < NEL; ++i) {
            float Yl, Yg;
            camY((int)i, v0, v1, v2, md, lw1, lb1, gw1, gb1, f32, Yl, Yg);
            float zl = fmaxf((Yl - m_l) * is_l, 0.f);
            float zg = fmaxf((Yg - m_g) * is_g, 0.f);
            float dzl = zl - mzl, dzg = zg - mzg;
            float xx[4] = {b2f(v0[i]), b2f(v1[i]), b2f(v2[i]), ldf(md, i, f32)};
            float s = 0.f;
#pragma unroll
            for (int c = 0; c < 4; ++c) {
                float t2 = wl2[c] * dzl + wg2[c] * dzg;
                s += xx[c] / (1.f + expf(-t2));
            }
            sumx[i] = 0.25f * s;
        }
    }
}

// ---------------- collapsed MLP head (parallel, multi-kernel) ----------------
__global__ void mlp_a(const void* __restrict__ mW3, const void* __restrict__ mW4,
                      const void* __restrict__ mb2, const void* __restrict__ mb3,
                      const void* __restrict__ mb4,
                      float* __restrict__ u3g, float* __restrict__ u2g,
                      float* __restrict__ sF, const int* __restrict__ fdt)
{
    __shared__ float u3[64];
    __shared__ float red[4];
    const int f32 = fdt[0];
    int t = threadIdx.x;
    if (t < 64) { float v = ldf(mW4, t, f32); u3[t] = v; u3g[t] = v; }
    __syncthreads();
    float part = 0.f;
    for (int k = t; k < 512; k += 256) {
        float s = 0.f;
#pragma unroll
        for (int o = 0; o < 64; ++o) s += ldf(mW3, o * 512 + k, f32) * u3[o];
        u2g[k] = s;
        part += ldf(mb2, k, f32) * s;
    }
    if (t < 64) part += ldf(mb3, t, f32) * u3[t];
    for (int o = 32; o; o >>= 1) part += __shfl_down(part, o);
    if ((t & 63) == 0) red[t >> 6] = part;
    __syncthreads();
    if (t == 0) sF[15] = red[0] + red[1] + red[2] + red[3] + ldf(mb4, 0, f32);
}

__global__ void mlp_b1(const void* __restrict__ mW2, const float* __restrict__ u2g,
                       float* __restrict__ part1, const int* __restrict__ fdt)
{
    int k = blockIdx.x * 256 + threadIdx.x;
    int o0 = blockIdx.y * 64;
    const int f32 = fdt[0];
    float s = 0.f;
#pragma unroll
    for (int oi = 0; oi < 64; ++oi) s += ldf(mW2, (long)(o0 + oi) * 1024 + k, f32) * u2g[o0 + oi];
    part1[blockIdx.y * 1024 + k] = s;
}

__global__ void mlp_b2(const float* __restrict__ part1, float* __restrict__ u1g)
{
    int k = blockIdx.x * 256 + threadIdx.x;
    float s = 0.f;
#pragma unroll
    for (int ob = 0; ob < 8; ++ob) s += part1[ob * 1024 + k];
    u1g[k] = s;
}

__global__ void mlp_c(const void* __restrict__ mb1, const float* __restrict__ u1g,
                      float* __restrict__ sF, const int* __restrict__ fdt)
{
    __shared__ float red[4];
    int t = threadIdx.x;
    const int f32 = fdt[0];
    float p = 0.f;
    for (int k = t; k < 1024; k += 256) p += ldf(mb1, k, f32) * u1g[k];
    for (int o = 32; o; o >>= 1) p += __shfl_down(p, o);
    if ((t & 63) == 0) red[t >> 6] = p;
    __syncthreads();
    if (t == 0) sF[14] = sF[15] + red[0] + red[1] + red[2] + red[3];
}

__global__ void mlp_u0s1(const void* __restrict__ mW1, const float* __restrict__ u1g,
                         float* __restrict__ part0, const int* __restrict__ fdt)
{
    int k = blockIdx.x * 256 + threadIdx.x;
    if (k >= 1802) return;
    int o0 = blockIdx.y * 64;
    const int f32 = fdt[0];
    float s = 0.f;
#pragma unroll
    for (int oi = 0; oi < 64; ++oi) s += ldf(mW1, (long)(o0 + oi) * 1802 + k, f32) * u1g[o0 + oi];
    part0[blockIdx.y * 2048 + k] = s;
}

__global__ void mlp_u0s2(const float* __restrict__ part0, float* __restrict__ u0)
{
    int k = blockIdx.x * 256 + threadIdx.x;
    if (k >= 1802) return;
    float s = 0.f;
#pragma unroll
    for (int ob = 0; ob < 16; ++ob) s += part0[ob * 2048 + k];
    u0[k] = s;
}

__global__ void rowdot(const float* __restrict__ sumx, const float* __restrict__ u0,
                       float* __restrict__ f, float* __restrict__ g)
{
    int r = blockIdx.x, t = threadIdx.x;
    float fa = 0.f, ga = 0.f;
    for (int o = t; o < OUTF; o += 256) {
        float v = sumx[(long)r * OUTF + o];
        fa += v * u0[o];
        ga += v * u0[OUTF + o];
    }
    for (int o = 32; o; o >>= 1) { fa += __shfl_down(fa, o); ga += __shfl_down(ga, o); }
    __shared__ float s[4][2];
    int lane = t & 63, wv = t >> 6;
    if (!lane) { s[wv][0] = fa; s[wv][1] = ga; }
    __syncthreads();
    if (t == 0) {
        f[r] = s[0][0] + s[1][0] + s[2][0] + s[3][0];
        g[r] = s[0][1] + s[1][1] + s[2][1] + s[3][1];
    }
}

__global__ void score(const int* __restrict__ ts, const float* __restrict__ f,
                      const float* __restrict__ g, const float* __restrict__ sF,
                      void* __restrict__ out, const int* __restrict__ fdt)
{
    int p = blockIdx.x * 256 + threadIdx.x;
    if (p >= 4096) return;
    float v = sane(f[ts[2 * p]] + g[ts[2 * p + 1]] + sF[14]);
    if (fdt[0]) ((float*)out)[p] = v;
    else        ((__hip_bfloat16*)out)[p] = f2b(v);
}

// ---------------- launch ----------------
extern "C" void kernel_launch(void* const* d_in, const int* in_sizes, int n_in,
                              void* d_out, int out_size, void* d_ws, size_t ws_size,
                              hipStream_t stream)
{
    const int NVv[3]   = {2060, 2459, 3929};
    const int NVPv[3]  = {2176, 2560, 3968};
    const int IOFFv[3] = {282, 681, 2151};
    const int ADJ_I[3] = {0, 1, 2}, FEAT_I[3] = {4, 5, 6}, W_I[3] = {8, 12, 16},
              AS_I[3] = {9, 13, 17}, AD_I[3] = {10, 14, 18}, BV_I[3] = {11, 15, 19};

    char* w = (char*)d_ws;
    size_t off = 0;
    auto alloc = [&](size_t b) { void* p = w + off; off += (b + 255) & ~(size_t)255; return p; };

    ushort* hT   = (ushort*)alloc(1024ULL * 3968 * 2);            // 8.1 MB
    ushort* Pexp = (ushort*)alloc(1792ULL * 3968 * 2);            // 14.2 MB
    __hip_bfloat16* voutb[3];
    for (int v = 0; v < 3; ++v)
        voutb[v] = (__hip_bfloat16*)alloc((size_t)NROWS * OUTF * 2);  // 3x 3.2 MB
    // asrc/adst/lrow contiguous (each size multiple of 256B) -> single zerof
    float*  asrc   = (float*)alloc(3968 * 4);
    float*  adst   = (float*)alloc(3968 * 4);
    float*  lrow   = (float*)alloc(1792 * 4);
    float*  statsF = (float*)alloc(16 * 4);
    float*  u3g    = (float*)alloc(64 * 4);
    float*  u2g    = (float*)alloc(512 * 4);
    float*  u1     = (float*)alloc(1024 * 4);
    float*  u0     = (float*)alloc(1802 * 4);
    float*  part1  = (float*)alloc(8 * 1024 * 4);
    float*  part0  = (float*)alloc(16 * 2048 * 4);
    float*  fv     = (float*)alloc(NROWS * 4);
    float*  gv     = (float*)alloc(NROWS * 4);
    int*    fdt    = (int*)alloc(4);
    float4* cp1    = (float4*)alloc(CAMNB * 16);
    float4* cp2    = (float4*)alloc(CAMNB * 16);
    // fast-path-only: featPad allocated last so the compact set fits small ws
    ushort* featPad = (ushort*)alloc(3968ULL * 3968 * 2);         // 31.5 MB
    const bool use_fast = (ws_size >= off);
    // overlays on dead regions
    ushort* Wpad = Pexp;            // Wpad (8.1 MB) lives in Pexp (14.2 MB) during gemm1
    float*  sumx = (float*)hT;      // hT dead after view loop; sumx 6.4 MB < 8.1 MB

    probe_dtype<<<1, 256, 0, stream>>>((const ushort*)d_in[9], fdt);

    for (int v = 0; v < 3; ++v) {
        int Nv = NVv[v], Nvp = NVPv[v], ioff2 = IOFFv[v];
        int Kp = (Nv + 63) & ~63;

        dim3 gg1(Nvp / 128, 8);   // hT[1024, Nvp] = W · feat^T
        if (use_fast) {
            dim3 gpk((Nvp / 8 + 255) / 256, Nvp);
            pack_dual<<<gpk, 256, 0, stream>>>((__hip_bfloat16*)featPad, d_in[FEAT_I[v]],
                                               Nv, Nv, Nv, Nvp, fdt);
            dim3 gpw((Nvp / 8 + 255) / 256, 1024);
            pack_dual<<<gpw, 256, 0, stream>>>((__hip_bfloat16*)Wpad, d_in[W_I[v]],
                                               901, Nv, Nv, Nvp, fdt);
            // B (featPad) is the big operand -> cluster same-x per XCD
            gemm_fast<0, 1><<<gg1, 512, 0, stream>>>(Wpad, featPad, Nvp,
                (__hip_bfloat16*)hT, Nvp, nullptr, nullptr, nullptr, 0, 0, fdt);
        } else {
            gemm1_raw<<<gg1, 256, 0, stream>>>(d_in[W_I[v]], d_in[FEAT_I[v]], Kp,
                                               Nv, Nv, 901, Nv, Nv,
                                               (__hip_bfloat16*)hT, Nvp, fdt);
        }

        // zero asrc+adst+lrow in one shot (contiguous: 3968+3968+1792 floats)
        zerof<<<38, 256, 0, stream>>>(asrc, 3968 + 3968 + 1792);

        dim3 gsd((Nv + 255) / 256, 8);
        srcdst2<<<gsd, 256, 0, stream>>>((const __hip_bfloat16*)hT,
            d_in[AS_I[v]], d_in[AD_I[v]], Nv, Nvp, asrc, adst, fdt);

        dim3 gp(Nvp / 64, 28);
        pbuild<<<gp, 256, 0, stream>>>((const int*)d_in[ADJ_I[v]], asrc, adst, Nv, Nvp, ioff2,
                                       (__hip_bfloat16*)Pexp, lrow);

        dim3 gg2(8, 14);          // vout[1778,901] = relu(P·h / l + b)
        // A (Pexp) is the big operand -> cluster same-y per XCD
        gemm_fast<1, 0><<<gg2, 512, 0, stream>>>(Pexp, hT, Nvp,
            nullptr, 0, lrow, d_in[BV_I[v]], voutb[v], NROWS, OUTF, fdt);
    }

    cam_pass1<<<CAMNB, 256, 0, stream>>>(voutb[0], voutb[1], voutb[2], d_in[7],
        d_in[20], d_in[21], d_in[24], d_in[25], cp1, fdt);
    cam_fin1<<<1, 256, 0, stream>>>(cp1, statsF);
    cam_pass2<<<CAMNB, 256, 0, stream>>>(voutb[0], voutb[1], voutb[2], d_in[7],
        d_in[20], d_in[21], d_in[24], d_in[25], statsF, cp2, fdt);
    cam_fin2<<<1, 256, 0, stream>>>(cp2, statsF, d_in[22], d_in[26], fdt);
    cam_fuse<<<CAMNB, 256, 0, stream>>>(voutb[0], voutb[1], voutb[2], d_in[7],
        d_in[20], d_in[21], d_in[24], d_in[25], statsF, sumx, fdt);

    // collapsed MLP head, parallelized
    mlp_a<<<1, 256, 0, stream>>>(d_in[32], d_in[34], d_in[31], d_in[33], d_in[35],
                                 u3g, u2g, statsF, fdt);
    mlp_b1<<<dim3(4, 8), 256, 0, stream>>>(d_in[30], u2g, part1, fdt);
    mlp_b2<<<4, 256, 0, stream>>>(part1, u1);
    mlp_c<<<1, 256, 0, stream>>>(d_in[29], u1, statsF, fdt);
    mlp_u0s1<<<dim3(8, 16), 256, 0, stream>>>(d_in[28], u1, part0, fdt);
    mlp_u0s2<<<8, 256, 0, stream>>>(part0, u0);

    rowdot<<<NROWS, 256, 0, stream>>>(sumx, u0, fv, gv);
    score<<<16, 256, 0, stream>>>((const int*)d_in[3], fv, gv, statsF, d_out, fdt);
}

// Round 7
// 789.038 us; speedup vs baseline: 1.1417x; 1.0258x over previous
//
#include <hip/hip_runtime.h>
#include <hip/hip_bf16.h>
#include <stdint.h>

typedef __attribute__((ext_vector_type(8))) short short8;
typedef __attribute__((ext_vector_type(4))) float f32x4;

#define AS1 __attribute__((address_space(1)))
#define AS3 __attribute__((address_space(3)))

#define NEL 1601978   // 1778*901
#define NROWS 1778
#define OUTF 901
#define CAMNB 783     // ceil(NEL / (256*8))

__device__ __forceinline__ float b2f(__hip_bfloat16 x) { return __bfloat162float(x); }
__device__ __forceinline__ __hip_bfloat16 f2b(float x) { return __float2bfloat16(x); }
__device__ __forceinline__ float sane(float v) { return isfinite(v) ? v : 0.f; }

// dtype-dual load: flag==1 -> fp32 array, flag==0 -> bf16 array
__device__ __forceinline__ float ldf(const void* p, long i, int f32)
{
    return f32 ? ((const float*)p)[i] : b2f(((const __hip_bfloat16*)p)[i]);
}

// 8-wide vector loads (base must be 8-aligned in elements)
__device__ __forceinline__ void ld8b(const __hip_bfloat16* p, long base, float* out)
{
    short8 t = *(const short8*)(p + base);
#pragma unroll
    for (int e = 0; e < 8; ++e) out[e] = __uint_as_float(((uint)(ushort)t[e]) << 16);
}
__device__ __forceinline__ void ld8d(const void* p, long base, int f32, float* out)
{
    if (f32) {
        const float4* q = (const float4*)((const float*)p + base);
        float4 a = q[0], b = q[1];
        out[0]=a.x; out[1]=a.y; out[2]=a.z; out[3]=a.w;
        out[4]=b.x; out[5]=b.y; out[6]=b.z; out[7]=b.w;
    } else {
        short8 t = *(const short8*)((const __hip_bfloat16*)p + base);
#pragma unroll
        for (int e = 0; e < 8; ++e) out[e] = __uint_as_float(((uint)(ushort)t[e]) << 16);
    }
}

// ---------------- dtype probe ----------------
__global__ void probe_dtype(const ushort* __restrict__ p, int* __restrict__ fdt)
{
    int t = threadIdx.x;
    int cnt = 0;
    for (int i = t; i < 512; i += 256) {
        int ex = (p[i] >> 7) & 0xFF;
        if (ex >= 0x85) cnt++;
    }
    for (int o = 32; o; o >>= 1) cnt += __shfl_down(cnt, o);
    __shared__ int s[4];
    if ((t & 63) == 0) s[t >> 6] = cnt;
    __syncthreads();
    if (t == 0) fdt[0] = (s[0] + s[1] + s[2] + s[3] > 16) ? 1 : 0;
}

// ---------------- zero scratch ----------------
__global__ void zerof(float* __restrict__ p, int n)
{
    int i = blockIdx.x * 256 + threadIdx.x;
    if (i < n) p[i] = 0.f;
}

// ---------------- pack (fp32|bf16) -> padded bf16, 8 elems/thread ----------------
__global__ void pack_dual(__hip_bfloat16* __restrict__ dst, const void* __restrict__ src,
                          int rows_valid, int cols_valid, int src_ld, int dst_ld,
                          const int* __restrict__ fdt)
{
    int c0 = (blockIdx.x * 256 + threadIdx.x) * 8;
    int r = blockIdx.y;
    if (c0 >= dst_ld) return;
    const int f32 = fdt[0];
    short8 out;
    if (r < rows_valid) {
        long base = (long)r * src_ld;
#pragma unroll
        for (int e = 0; e < 8; ++e) {
            int c = c0 + e;
            float v = (c < cols_valid) ? ldf(src, base + c, f32) : 0.f;
            out[e] = (short)__hip_bfloat16_raw(f2b(v)).x;
        }
    } else {
#pragma unroll
        for (int e = 0; e < 8; ++e) out[e] = 0;
    }
    *(short8*)(dst + (long)r * dst_ld + c0) = out;
}

// ---------------- vector-staged bf16 GEMM: C = A(M,K) * B(N,K)^T ----------------
// Round-7: tile shape templated (BM x BN, BK=64, 32x32 per wave) so grids
// exceed 256 blocks -> 2+ blocks/CU co-resident. Round-6 counters showed the
// per-step vmcnt(0) drain waits on raw LDS-DMA transfer (~1200-2000cy/step,
// per-CU L2 share) with NOTHING to hide it at 1 block/CU (grid<=248). Cross-
// block overlap (m97's regime: one block's DMA under another's MFMA) is the
// fix; in-block pipelining already failed (round 4).
//   gg1: BM=128,BN=64, 512thr, LDS 48KB -> grids 272/320/496 (~2/CU, 3 fit)
//   gg2: BM= 64,BN=64, 256thr, LDS 32KB -> grid 448 (was 112!) (~2/CU, 5 fit)
// Schedule / T2 involution / T1 XCD swizzle = round-3 proven form (BK=64).
// K-accumulation order = round-3 (verified, same absmax).
// EPI 0: store bf16 C[m*ldc+n].  EPI 1: relu(C/l[m] + bias[n]) -> bf16 vout.
template<int EPI, int XMAJ, int BM, int BN>
__global__ __launch_bounds__((BM / 32) * (BN / 32) * 64)
void gemm_fast(const ushort* __restrict__ A, const ushort* __restrict__ B, int K,
               __hip_bfloat16* __restrict__ Cbf, int ldc,
               const float* __restrict__ lrow, const void* __restrict__ bias,
               __hip_bfloat16* __restrict__ vout, int Mvalid, int Nvalid,
               const int* __restrict__ fdt)
{
    constexpr int WN  = BN / 32;                 // waves along N
    constexpr int NT  = (BM / 32) * (BN / 32) * 64;
    constexpr int RPI = NT / 8;                  // rows staged per iteration
    __shared__ __align__(16) ushort sA[2][BM * 64];
    __shared__ __align__(16) ushort sB[2][BN * 64];
    const int tid = threadIdx.x;
    const int lane = tid & 63;
    const int wid = tid >> 6;
    const int wm = (wid / WN) * 32;
    const int wn = (wid % WN) * 32;

    // T1: chunked bijective XCD swizzle (all grids %8==0)
    const int gx = gridDim.x, gy = gridDim.y;
    int lid = blockIdx.y * gx + blockIdx.x;
    int bx, by;
    const int n = gx * gy;
    if ((n & 7) == 0) {
        int q = n >> 3;
        int pos = (lid & 7) * q + (lid >> 3);
        if (XMAJ) { bx = pos / gy; by = pos - bx * gy; }
        else      { by = pos / gx; bx = pos - by * gx; }
    } else {
        bx = blockIdx.x; by = blockIdx.y;
    }
    const long m0 = (long)by * BM;
    const long n0 = (long)bx * BN;

    f32x4 acc[2][2];
#pragma unroll
    for (int i = 0; i < 2; ++i)
#pragma unroll
        for (int j = 0; j < 2; ++j) acc[i][j] = (f32x4){0.f, 0.f, 0.f, 0.f};

    // staging map: row = it*RPI + (tid>>3), chunk = tid&7 (lane-linear LDS)
    const int srow = tid >> 3;
    const int scol = tid & 7;
    const int csub = scol * 8;                    // LDS chunk (linear, required)
    const int gsub = (scol ^ (srow & 7)) * 8;     // pre-swizzled GLOBAL chunk
    const int kgrp = lane >> 4;
    const int rowf = lane & 15;
    const int rx = rowf & 7;                      // read-side swizzle key

    auto stage = [&](int buf, int k0) {
#pragma unroll
        for (int it = 0; it < BM / RPI; ++it) {
            int r = it * RPI + srow;
            __builtin_amdgcn_global_load_lds(
                (const AS1 uint*)(const void*)(A + (m0 + r) * (long)K + k0 + gsub),
                (AS3 uint*)&sA[buf][r * 64 + csub], 16, 0, 0);
        }
#pragma unroll
        for (int it = 0; it < BN / RPI; ++it) {
            int r = it * RPI + srow;
            __builtin_amdgcn_global_load_lds(
                (const AS1 uint*)(const void*)(B + (n0 + r) * (long)K + k0 + gsub),
                (AS3 uint*)&sB[buf][r * 64 + csub], 16, 0, 0);
        }
    };

    stage(0, 0);
    __syncthreads();                   // cold-start drain, once

    int cur = 0;
    for (int k0 = 0; k0 < K; k0 += 64) {
        if (k0 + 64 < K) stage(cur ^ 1, k0 + 64);   // prefetch next tile first
#pragma unroll
        for (int ks = 0; ks < 64; ks += 32) {
            short8 af[2], bfr[2];
            const int kc = (ks >> 3) + kgrp;        // logical 16B chunk 0..7
            const int kb = ((kc ^ rx) << 3);        // swizzled storage offset
#pragma unroll
            for (int f = 0; f < 2; ++f)
                af[f]  = *(const short8*)(&sA[cur][(wm + f * 16 + rowf) * 64 + kb]);
#pragma unroll
            for (int f = 0; f < 2; ++f)
                bfr[f] = *(const short8*)(&sB[cur][(wn + f * 16 + rowf) * 64 + kb]);
#pragma unroll
            for (int i = 0; i < 2; ++i)
#pragma unroll
                for (int j = 0; j < 2; ++j)
                    acc[i][j] = __builtin_amdgcn_mfma_f32_16x16x32_bf16(af[i], bfr[j], acc[i][j], 0, 0, 0);
        }
        __syncthreads();   // drains vmcnt(0) (prefetch done) + lgkmcnt(0) (reads done)
        cur ^= 1;
    }

    const int f32 = (EPI == 1) ? fdt[0] : 0;
    const int rq = (lane >> 4) * 4;   // C/D: col = lane&15, row = (lane>>4)*4 + reg
#pragma unroll
    for (int i = 0; i < 2; ++i)
#pragma unroll
        for (int j = 0; j < 2; ++j)
#pragma unroll
            for (int rg = 0; rg < 4; ++rg) {
                long m = m0 + wm + i * 16 + rq + rg;
                long n2 = n0 + wn + j * 16 + (lane & 15);
                float v = acc[i][j][rg];
                if constexpr (EPI == 0) {
                    Cbf[m * ldc + n2] = f2b(v);
                } else {
                    if (m < Mvalid && n2 < Nvalid) {
                        float den = fmaxf(lrow[m], 1e-30f);
                        float r = v / den + ldf(bias, n2, f32);
                        vout[m * Nvalid + n2] = f2b(sane(fmaxf(r, 0.f)));
                    }
                }
            }
}

// ---------------- GEMM1 fallback: raw operands, dtype-dual scalar staging ----------------
__global__ __launch_bounds__(256)
void gemm1_raw(const void* __restrict__ A, const void* __restrict__ B, int K,
               int lda, int ldb, int Ma, int Nb, int Kv,
               __hip_bfloat16* __restrict__ Cbf, int ldc, const int* __restrict__ fdt)
{
    __shared__ __align__(16) ushort sA[128 * 64];
    __shared__ __align__(16) ushort sB[128 * 64];
    const int f32 = fdt[0];
    const int tid = threadIdx.x;
    const int lane = tid & 63;
    const int wid = tid >> 6;
    const int wm = (wid >> 1) * 64;
    const int wn = (wid & 1) * 64;
    const long m0 = (long)blockIdx.y * 128;
    const long n0 = (long)blockIdx.x * 128;

    f32x4 acc[4][4];
#pragma unroll
    for (int i = 0; i < 4; ++i)
#pragma unroll
        for (int j = 0; j < 4; ++j) acc[i][j] = (f32x4){0.f, 0.f, 0.f, 0.f};

    const int lr = tid >> 3;
    const int lc = (tid & 7) * 8;
    const int koff = (lane >> 4) * 8;
    const int rowf = lane & 15;

    for (int k0 = 0; k0 < K; k0 += 64) {
        __syncthreads();
#pragma unroll
        for (int it = 0; it < 4; ++it) {
            int r = it * 32 + lr;
            long gm = m0 + r, gn = n0 + r;
            ushort va[8], vb[8];
#pragma unroll
            for (int e = 0; e < 8; ++e) {
                int k = k0 + lc + e;
                bool kok = (k < Kv);
                float fa = (kok && gm < Ma) ? ldf(A, gm * (long)lda + k, f32) : 0.f;
                float fb = (kok && gn < Nb) ? ldf(B, gn * (long)ldb + k, f32) : 0.f;
                va[e] = __hip_bfloat16_raw(f2b(fa)).x;
                vb[e] = __hip_bfloat16_raw(f2b(fb)).x;
            }
#pragma unroll
            for (int e = 0; e < 8; ++e) { sA[r * 64 + lc + e] = va[e]; sB[r * 64 + lc + e] = vb[e]; }
        }
        __syncthreads();
#pragma unroll
        for (int ks = 0; ks < 64; ks += 32) {
            short8 af[4], bfr[4];
            int kb = ks + koff;
#pragma unroll
            for (int f = 0; f < 4; ++f) {
                af[f]  = *(const short8*)(&sA[(wm + f * 16 + rowf) * 64 + kb]);
                bfr[f] = *(const short8*)(&sB[(wn + f * 16 + rowf) * 64 + kb]);
            }
#pragma unroll
            for (int i = 0; i < 4; ++i)
#pragma unroll
                for (int j = 0; j < 4; ++j)
                    acc[i][j] = __builtin_amdgcn_mfma_f32_16x16x32_bf16(af[i], bfr[j], acc[i][j], 0, 0, 0);
        }
    }

    const int rq = (lane >> 4) * 4;
#pragma unroll
    for (int i = 0; i < 4; ++i)
#pragma unroll
        for (int j = 0; j < 4; ++j)
#pragma unroll
            for (int rg = 0; rg < 4; ++rg) {
                long m = m0 + wm + i * 16 + rq + rg;
                long n = n0 + wn + j * 16 + (lane & 15);
                Cbf[m * ldc + n] = f2b(acc[i][j][rg]);
            }
}

// ---------------- asrc/adst: parallel over (j, o-chunks), atomic accumulate ----------------
__global__ void srcdst2(const __hip_bfloat16* __restrict__ hT,
                        const void* __restrict__ a_src, const void* __restrict__ a_dst,
                        int Nv, int Nvp, float* __restrict__ asrc, float* __restrict__ adst,
                        const int* __restrict__ fdt)
{
    const int f32 = fdt[0];
    int j = blockIdx.x * 256 + threadIdx.x;
    if (j >= Nv) return;
    int o0 = blockIdx.y * 113;
    int o1 = min(OUTF, o0 + 113);
    float s1 = 0.f, s2 = 0.f;
    for (int o = o0; o < o1; ++o) {
        float hv = b2f(hT[(long)o * Nvp + j]);
        s1 += hv * ldf(a_src, o, f32);
        s2 += hv * ldf(a_dst, o, f32);
    }
    atomicAdd(&asrc[j], s1);
    atomicAdd(&adst[j], s2);
}

// ---------------- P = mask * exp(leaky(adst_i + asrc_j)), row sums l ----------------
// Lane-local row-sum restructure (round-6, verified).
__global__ void pbuild(const int* __restrict__ adj, const float* __restrict__ asrc,
                       const float* __restrict__ adst, int Nv, int Nvp, int ioff,
                       __hip_bfloat16* __restrict__ P, float* __restrict__ l)
{
    __shared__ int   sAdj[64][65];   // [j-local][r-local]
    __shared__ float sP[64][65];     // [r-local][j-local], bf16-rounded p
    __shared__ float sAs[64];
    __shared__ float sL[4][64];
    const int tid = threadIdx.x;
    const int lane = tid & 63, grp = tid >> 6;
    const int j0 = blockIdx.x * 64, r0 = blockIdx.y * 64;

    const int r = r0 + lane;
    const bool rv = (r < NROWS);
    const int i = (r < 901) ? r : r + ioff;

    if (tid < 64) sAs[tid] = (j0 + tid < Nv) ? asrc[j0 + tid] : 0.f;
#pragma unroll
    for (int it = 0; it < 16; ++it) {
        int jr = it * 4 + grp;
        int j = j0 + jr;
        int v = 0;
        if (j < Nv && rv) v = adj[(long)j * Nv + i];
        sAdj[jr][lane] = v;
    }
    const float adstv = rv ? adst[i] : 0.f;
    __syncthreads();

    float lsum = 0.f;
#pragma unroll
    for (int jj = 0; jj < 16; ++jj) {
        int jl = grp * 16 + jj;
        int j = j0 + jl;
        float p = 0.f;
        if (rv && j < Nv) {
            bool m = (sAdj[jl][lane] != 0) || (i == j);
            if (m) {
                float e = adstv + sAs[jl];
                e = e > 0.f ? e : 0.2f * e;
                p = expf(fminf(e, 30.f));
            }
        }
        float pr = b2f(f2b(p));
        sP[lane][jl] = pr;
        lsum += pr;
    }
    sL[grp][lane] = lsum;
    __syncthreads();

    if (grp == 0 && rv) {
        float t = sL[0][lane] + sL[1][lane] + sL[2][lane] + sL[3][lane];
        atomicAdd(&l[r], t);
    }

#pragma unroll
    for (int it = 0; it < 16; ++it) {
        int rr = it * 4 + grp;
        P[(long)(r0 + rr) * Nvp + (j0 + lane)] = f2b(sP[rr][lane]);
    }
}

// ---------------- CAM (vectorized, zero-atomic two-stage reduction) ----------------
__device__ __forceinline__ void block_part4(float a, float b, float c, float d, float4* out)
{
    for (int o = 32; o; o >>= 1) {
        a += __shfl_down(a, o); b += __shfl_down(b, o);
        c += __shfl_down(c, o); d += __shfl_down(d, o);
    }
    __shared__ float s[4][4];
    int lane = threadIdx.x & 63, wv = threadIdx.x >> 6;
    if (lane == 0) { s[wv][0] = a; s[wv][1] = b; s[wv][2] = c; s[wv][3] = d; }
    __syncthreads();
    if (threadIdx.x == 0)
        *out = make_float4(s[0][0] + s[1][0] + s[2][0] + s[3][0],
                           s[0][1] + s[1][1] + s[2][1] + s[3][1],
                           s[0][2] + s[1][2] + s[2][2] + s[3][2],
                           s[0][3] + s[1][3] + s[2][3] + s[3][3]);
}

__device__ __forceinline__ void camY(int idx,
    const __hip_bfloat16* v0, const __hip_bfloat16* v1, const __hip_bfloat16* v2,
    const void* md, const void* lw1, const void* lb1, const void* gw1, const void* gb1,
    int f32, float& Yl, float& Yg)
{
    float x0 = b2f(v0[idx]), x1 = b2f(v1[idx]), x2 = b2f(v2[idx]), x3 = ldf(md, idx, f32);
    Yl = ldf(lw1,0,f32)*x0 + ldf(lw1,1,f32)*x1 + ldf(lw1,2,f32)*x2 + ldf(lw1,3,f32)*x3 + ldf(lb1,0,f32);
    Yg = ldf(gw1,0,f32)*x0 + ldf(gw1,1,f32)*x1 + ldf(gw1,2,f32)*x2 + ldf(gw1,3,f32)*x3 + ldf(gb1,0,f32);
}

// vector camY: 8 elements at base (base%8==0, base+8<=NEL)
__device__ __forceinline__ void camY8(long base,
    const __hip_bfloat16* v0, const __hip_bfloat16* v1, const __hip_bfloat16* v2,
    const void* md, const void* lw1, const void* lb1, const void* gw1, const void* gb1,
    int f32, float* Yl, float* Yg, float x[4][8])
{
    ld8b(v0, base, x[0]); ld8b(v1, base, x[1]); ld8b(v2, base, x[2]);
    ld8d(md, base, f32, x[3]);
    float wl0 = ldf(lw1,0,f32), wl1 = ldf(lw1,1,f32), wl2 = ldf(lw1,2,f32), wl3 = ldf(lw1,3,f32);
    float wg0 = ldf(gw1,0,f32), wg1 = ldf(gw1,1,f32), wg2 = ldf(gw1,2,f32), wg3 = ldf(gw1,3,f32);
    float bl = ldf(lb1,0,f32), bg = ldf(gb1,0,f32);
#pragma unroll
    for (int e = 0; e < 8; ++e) {
        Yl[e] = wl0*x[0][e] + wl1*x[1][e] + wl2*x[2][e] + wl3*x[3][e] + bl;
        Yg[e] = wg0*x[0][e] + wg1*x[1][e] + wg2*x[2][e] + wg3*x[3][e] + bg;
    }
}

__global__ void cam_pass1(const __hip_bfloat16* __restrict__ v0, const __hip_bfloat16* __restrict__ v1,
                          const __hip_bfloat16* __restrict__ v2, const void* __restrict__ md,
                          const void* __restrict__ lw1, const void* __restrict__ lb1,
                          const void* __restrict__ gw1, const void* __restrict__ gb1,
                          float4* __restrict__ part, const int* __restrict__ fdt)
{
    long base = ((long)blockIdx.x * 256 + threadIdx.x) * 8;
    float a = 0, b = 0, c = 0, d = 0;
    const int f32 = fdt[0];
    if (base + 8 <= NEL) {
        float Yl[8], Yg[8], x[4][8];
        camY8(base, v0, v1, v2, md, lw1, lb1, gw1, gb1, f32, Yl, Yg, x);
#pragma unroll
        for (int e = 0; e < 8; ++e) { a += Yl[e]; b += Yl[e]*Yl[e]; c += Yg[e]; d += Yg[e]*Yg[e]; }
    } else if (base < NEL) {
        for (long i = base; i < NEL; ++i) {
            float Yl, Yg;
            camY((int)i, v0, v1, v2, md, lw1, lb1, gw1, gb1, f32, Yl, Yg);
            a += Yl; b += Yl*Yl; c += Yg; d += Yg*Yg;
        }
    }
    block_part4(a, b, c, d, &part[blockIdx.x]);
}

__global__ void cam_fin1(const float4* __restrict__ part, float* __restrict__ sF)
{
    int t = threadIdx.x;
    double a = 0, b = 0, c = 0, d = 0;
    for (int i = t; i < CAMNB; i += 256) {
        float4 p = part[i];
        a += p.x; b += p.y; c += p.z; d += p.w;
    }
    for (int o = 32; o; o >>= 1) {
        a += __shfl_down(a, o); b += __shfl_down(b, o);
        c += __shfl_down(c, o); d += __shfl_down(d, o);
    }
    __shared__ double sd[4][4];
    int lane = t & 63, wv = t >> 6;
    if (!lane) { sd[wv][0] = a; sd[wv][1] = b; sd[wv][2] = c; sd[wv][3] = d; }
    __syncthreads();
    if (t == 0) {
        double n = (double)NEL;
        double A = sd[0][0]+sd[1][0]+sd[2][0]+sd[3][0];
        double B = sd[0][1]+sd[1][1]+sd[2][1]+sd[3][1];
        double C = sd[0][2]+sd[1][2]+sd[2][2]+sd[3][2];
        double D = sd[0][3]+sd[1][3]+sd[2][3]+sd[3][3];
        double ml = A / n, vl = B / n - ml * ml;
        double mg = C / n, vg = D / n - mg * mg;
        if (vl < 0.0) vl = 0.0;
        if (vg < 0.0) vg = 0.0;
        sF[0] = (float)ml; sF[1] = (float)(1.0 / sqrt(vl + 1e-5));
        sF[2] = (float)mg; sF[3] = (float)(1.0 / sqrt(vg + 1e-5));
    }
}

__global__ void cam_pass2(const __hip_bfloat16* __restrict__ v0, const __hip_bfloat16* __restrict__ v1,
                          const __hip_bfloat16* __restrict__ v2, const void* __restrict__ md,
                          const void* __restrict__ lw1, const void* __restrict__ lb1,
                          const void* __restrict__ gw1, const void* __restrict__ gb1,
                          const float* __restrict__ sF, float4* __restrict__ part,
                          const int* __restrict__ fdt)
{
    long base = ((long)blockIdx.x * 256 + threadIdx.x) * 8;
    float a = 0, b = 0, c = 0, d = 0;
    const int f32 = fdt[0];
    const float m_l = sF[0], is_l = sF[1], m_g = sF[2], is_g = sF[3];
    if (base + 8 <= NEL) {
        float Yl[8], Yg[8], x[4][8];
        camY8(base, v0, v1, v2, md, lw1, lb1, gw1, gb1, f32, Yl, Yg, x);
#pragma unroll
        for (int e = 0; e < 8; ++e) {
            float zl = fmaxf((Yl[e] - m_l) * is_l, 0.f);
            float zg = fmaxf((Yg[e] - m_g) * is_g, 0.f);
            a += zl; b += zl*zl; c += zg; d += zg*zg;
        }
    } else if (base < NEL) {
        for (long i = base; i < NEL; ++i) {
            float Yl, Yg;
            camY((int)i, v0, v1, v2, md, lw1, lb1, gw1, gb1, f32, Yl, Yg);
            float zl = fmaxf((Yl - m_l) * is_l, 0.f);
            float zg = fmaxf((Yg - m_g) * is_g, 0.f);
            a += zl; b += zl*zl; c += zg; d += zg*zg;
        }
    }
    block_part4(a, b, c, d, &part[blockIdx.x]);
}

__global__ void cam_fin2(const float4* __restrict__ part, float* __restrict__ sF,
                         const void* __restrict__ lw2, const void* __restrict__ gw2,
                         const int* __restrict__ fdt)
{
    int t = threadIdx.x;
    double a = 0, b = 0, c = 0, d = 0;
    for (int i = t; i < CAMNB; i += 256) {
        float4 p = part[i];
        a += p.x; b += p.y; c += p.z; d += p.w;
    }
    for (int o = 32; o; o >>= 1) {
        a += __shfl_down(a, o); b += __shfl_down(b, o);
        c += __shfl_down(c, o); d += __shfl_down(d, o);
    }
    __shared__ double sd[4][4];
    int lane = t & 63, wv = t >> 6;
    if (!lane) { sd[wv][0] = a; sd[wv][1] = b; sd[wv][2] = c; sd[wv][3] = d; }
    __syncthreads();
    if (t == 0) {
        const int f32 = fdt[0];
        double n = (double)NEL;
        double A = sd[0][0]+sd[1][0]+sd[2][0]+sd[3][0];
        double B = sd[0][1]+sd[1][1]+sd[2][1]+sd[3][1];
        double C = sd[0][2]+sd[1][2]+sd[2][2]+sd[3][2];
        double D = sd[0][3]+sd[1][3]+sd[2][3]+sd[3][3];
        double mzl = A / n, vzl = B / n - mzl * mzl;
        double mzg = C / n, vzg = D / n - mzg * mzg;
        if (vzl < 0.0) vzl = 0.0;
        if (vzg < 0.0) vzg = 0.0;
        sF[4] = (float)mzl; sF[5] = (float)mzg;
        for (int c2 = 0; c2 < 4; ++c2) {
            double wl = (double)ldf(lw2, c2, f32);
            double wg = (double)ldf(gw2, c2, f32);
            sF[6 + c2]  = (float)(wl / sqrt(wl * wl * vzl + 1e-5));
            sF[10 + c2] = (float)(wg / sqrt(wg * wg * vzg + 1e-5));
        }
    }
}

__global__ void cam_fuse(const __hip_bfloat16* __restrict__ v0, const __hip_bfloat16* __restrict__ v1,
                         const __hip_bfloat16* __restrict__ v2, const void* __restrict__ md,
                         const void* __restrict__ lw1, const void* __restrict__ lb1,
                         const void* __restrict__ gw1, const void* __restrict__ gb1,
                         const float* __restrict__ sF, float* __restrict__ sumx,
                         const int* __restrict__ fdt)
{
    long base = ((long)blockIdx.x * 256 + threadIdx.x) * 8;
    if (base >= NEL) return;
    const int f32 = fdt[0];
    const float m_l = sF[0], is_l = sF[1], m_g = sF[2], is_g = sF[3];
    const float mzl = sF[4], mzg = sF[5];
    float wl2[4], wg2[4];
#pragma unroll
    for (int c = 0; c < 4; ++c) { wl2[c] = sF[6 + c]; wg2[c] = sF[10 + c]; }

    if (base + 8 <= NEL) {
        float Yl[8], Yg[8], x[4][8], sv[8];
        camY8(base, v0, v1, v2, md, lw1, lb1, gw1, gb1, f32, Yl, Yg, x);
#pragma unroll
        for (int e = 0; e < 8; ++e) {
            float zl = fmaxf((Yl[e] - m_l) * is_l, 0.f);
            float zg = fmaxf((Yg[e] - m_g) * is_g, 0.f);
            float dzl = zl - mzl, dzg = zg - mzg;
            float s = 0.f;
#pragma unroll
            for (int c = 0; c < 4; ++c) {
                float t2 = wl2[c] * dzl + wg2[c] * dzg;
                s += x[c][e] / (1.f + expf(-t2));
            }
            sv[e] = 0.25f * s;
        }
        *(float4*)(sumx + base)     = make_float4(sv[0], sv[1], sv[2], sv[3]);
        *(float4*)(sumx + base + 4) = make_float4(sv[4], sv[5], sv[6], sv[7]);
    } else {
        for (long i = base; i < NEL; ++i) {
            float Yl, Yg;
            camY((int)i, v0, v1, v2, md, lw1, lb1, gw1, gb1, f32, Yl, Yg);
            float zl = fmaxf((Yl - m_l) * is_l, 0.f);
            float zg = fmaxf((Yg - m_g) * is_g, 0.f);
            float dzl = zl - mzl, dzg = zg - mzg;
            float xx[4] = {b2f(v0[i]), b2f(v1[i]), b2f(v2[i]), ldf(md, i, f32)};
            float s = 0.f;
#pragma unroll
            for (int c = 0; c < 4; ++c) {
                float t2 = wl2[c] * dzl + wg2[c] * dzg;
                s += xx[c] / (1.f + expf(-t2));
            }
            sumx[i] = 0.25f * s;
        }
    }
}

// ---------------- collapsed MLP head (parallel, multi-kernel) ----------------
__global__ void mlp_a(const void* __restrict__ mW3, const void* __restrict__ mW4,
                      const void* __restrict__ mb2, const void* __restrict__ mb3,
                      const void* __restrict__ mb4,
                      float* __restrict__ u3g, float* __restrict__ u2g,
                      float* __restrict__ sF, const int* __restrict__ fdt)
{
    __shared__ float u3[64];
    __shared__ float red[4];
    const int f32 = fdt[0];
    int t = threadIdx.x;
    if (t < 64) { float v = ldf(mW4, t, f32); u3[t] = v; u3g[t] = v; }
    __syncthreads();
    float part = 0.f;
    for (int k = t; k < 512; k += 256) {
        float s = 0.f;
#pragma unroll
        for (int o = 0; o < 64; ++o) s += ldf(mW3, o * 512 + k, f32) * u3[o];
        u2g[k] = s;
        part += ldf(mb2, k, f32) * s;
    }
    if (t < 64) part += ldf(mb3, t, f32) * u3[t];
    for (int o = 32; o; o >>= 1) part += __shfl_down(part, o);
    if ((t & 63) == 0) red[t >> 6] = part;
    __syncthreads();
    if (t == 0) sF[15] = red[0] + red[1] + red[2] + red[3] + ldf(mb4, 0, f32);
}

__global__ void mlp_b1(const void* __restrict__ mW2, const float* __restrict__ u2g,
                       float* __restrict__ part1, const int* __restrict__ fdt)
{
    int k = blockIdx.x * 256 + threadIdx.x;
    int o0 = blockIdx.y * 64;
    const int f32 = fdt[0];
    float s = 0.f;
#pragma unroll
    for (int oi = 0; oi < 64; ++oi) s += ldf(mW2, (long)(o0 + oi) * 1024 + k, f32) * u2g[o0 + oi];
    part1[blockIdx.y * 1024 + k] = s;
}

__global__ void mlp_b2(const float* __restrict__ part1, float* __restrict__ u1g)
{
    int k = blockIdx.x * 256 + threadIdx.x;
    float s = 0.f;
#pragma unroll
    for (int ob = 0; ob < 8; ++ob) s += part1[ob * 1024 + k];
    u1g[k] = s;
}

__global__ void mlp_c(const void* __restrict__ mb1, const float* __restrict__ u1g,
                      float* __restrict__ sF, const int* __restrict__ fdt)
{
    __shared__ float red[4];
    int t = threadIdx.x;
    const int f32 = fdt[0];
    float p = 0.f;
    for (int k = t; k < 1024; k += 256) p += ldf(mb1, k, f32) * u1g[k];
    for (int o = 32; o; o >>= 1) p += __shfl_down(p, o);
    if ((t & 63) == 0) red[t >> 6] = p;
    __syncthreads();
    if (t == 0) sF[14] = sF[15] + red[0] + red[1] + red[2] + red[3];
}

__global__ void mlp_u0s1(const void* __restrict__ mW1, const float* __restrict__ u1g,
                         float* __restrict__ part0, const int* __restrict__ fdt)
{
    int k = blockIdx.x * 256 + threadIdx.x;
    if (k >= 1802) return;
    int o0 = blockIdx.y * 64;
    const int f32 = fdt[0];
    float s = 0.f;
#pragma unroll
    for (int oi = 0; oi < 64; ++oi) s += ldf(mW1, (long)(o0 + oi) * 1802 + k, f32) * u1g[o0 + oi];
    part0[blockIdx.y * 2048 + k] = s;
}

__global__ void mlp_u0s2(const float* __restrict__ part0, float* __restrict__ u0)
{
    int k = blockIdx.x * 256 + threadIdx.x;
    if (k >= 1802) return;
    float s = 0.f;
#pragma unroll
    for (int ob = 0; ob < 16; ++ob) s += part0[ob * 2048 + k];
    u0[k] = s;
}

__global__ void rowdot(const float* __restrict__ sumx, const float* __restrict__ u0,
                       float* __restrict__ f, float* __restrict__ g)
{
    int r = blockIdx.x, t = threadIdx.x;
    float fa = 0.f, ga = 0.f;
    for (int o = t; o < OUTF; o += 256) {
        float v = sumx[(long)r * OUTF + o];
        fa += v * u0[o];
        ga += v * u0[OUTF + o];
    }
    for (int o = 32; o; o >>= 1) { fa += __shfl_down(fa, o); ga += __shfl_down(ga, o); }
    __shared__ float s[4][2];
    int lane = t & 63, wv = t >> 6;
    if (!lane) { s[wv][0] = fa; s[wv][1] = ga; }
    __syncthreads();
    if (t == 0) {
        f[r] = s[0][0] + s[1][0] + s[2][0] + s[3][0];
        g[r] = s[0][1] + s[1][1] + s[2][1] + s[3][1];
    }
}

__global__ void score(const int* __restrict__ ts, const float* __restrict__ f,
                      const float* __restrict__ g, const float* __restrict__ sF,
                      void* __restrict__ out, const int* __restrict__ fdt)
{
    int p = blockIdx.x * 256 + threadIdx.x;
    if (p >= 4096) return;
    float v = sane(f[ts[2 * p]] + g[ts[2 * p + 1]] + sF[14]);
    if (fdt[0]) ((float*)out)[p] = v;
    else        ((__hip_bfloat16*)out)[p] = f2b(v);
}

// ---------------- launch ----------------
extern "C" void kernel_launch(void* const* d_in, const int* in_sizes, int n_in,
                              void* d_out, int out_size, void* d_ws, size_t ws_size,
                              hipStream_t stream)
{
    const int NVv[3]   = {2060, 2459, 3929};
    const int NVPv[3]  = {2176, 2560, 3968};
    const int IOFFv[3] = {282, 681, 2151};
    const int ADJ_I[3] = {0, 1, 2}, FEAT_I[3] = {4, 5, 6}, W_I[3] = {8, 12, 16},
              AS_I[3] = {9, 13, 17}, AD_I[3] = {10, 14, 18}, BV_I[3] = {11, 15, 19};

    char* w = (char*)d_ws;
    size_t off = 0;
    auto alloc = [&](size_t b) { void* p = w + off; off += (b + 255) & ~(size_t)255; return p; };

    ushort* hT   = (ushort*)alloc(1024ULL * 3968 * 2);            // 8.1 MB
    ushort* Pexp = (ushort*)alloc(1792ULL * 3968 * 2);            // 14.2 MB
    __hip_bfloat16* voutb[3];
    for (int v = 0; v < 3; ++v)
        voutb[v] = (__hip_bfloat16*)alloc((size_t)NROWS * OUTF * 2);  // 3x 3.2 MB
    // asrc/adst/lrow contiguous (each size multiple of 256B) -> single zerof
    float*  asrc   = (float*)alloc(3968 * 4);
    float*  adst   = (float*)alloc(3968 * 4);
    float*  lrow   = (float*)alloc(1792 * 4);
    float*  statsF = (float*)alloc(16 * 4);
    float*  u3g    = (float*)alloc(64 * 4);
    float*  u2g    = (float*)alloc(512 * 4);
    float*  u1     = (float*)alloc(1024 * 4);
    float*  u0     = (float*)alloc(1802 * 4);
    float*  part1  = (float*)alloc(8 * 1024 * 4);
    float*  part0  = (float*)alloc(16 * 2048 * 4);
    float*  fv     = (float*)alloc(NROWS * 4);
    float*  gv     = (float*)alloc(NROWS * 4);
    int*    fdt    = (int*)alloc(4);
    float4* cp1    = (float4*)alloc(CAMNB * 16);
    float4* cp2    = (float4*)alloc(CAMNB * 16);
    // fast-path-only: featPad allocated last so the compact set fits small ws
    ushort* featPad = (ushort*)alloc(3968ULL * 3968 * 2);         // 31.5 MB
    const bool use_fast = (ws_size >= off);
    // overlays on dead regions
    ushort* Wpad = Pexp;            // Wpad (8.1 MB) lives in Pexp (14.2 MB) during gemm1
    float*  sumx = (float*)hT;      // hT dead after view loop; sumx 6.4 MB < 8.1 MB

    probe_dtype<<<1, 256, 0, stream>>>((const ushort*)d_in[9], fdt);

    for (int v = 0; v < 3; ++v) {
        int Nv = NVv[v], Nvp = NVPv[v], ioff2 = IOFFv[v];
        int Kp = (Nv + 63) & ~63;

        if (use_fast) {
            dim3 gpk((Nvp / 8 + 255) / 256, Nvp);
            pack_dual<<<gpk, 256, 0, stream>>>((__hip_bfloat16*)featPad, d_in[FEAT_I[v]],
                                               Nv, Nv, Nv, Nvp, fdt);
            dim3 gpw((Nvp / 8 + 255) / 256, 1024);
            pack_dual<<<gpw, 256, 0, stream>>>((__hip_bfloat16*)Wpad, d_in[W_I[v]],
                                               901, Nv, Nv, Nvp, fdt);
            // hT[1024, Nvp] = W · feat^T ; BM=128,BN=64 -> grid 272/320/496
            dim3 gg1(Nvp / 64, 8);
            // B (featPad) is the big operand -> cluster same-x per XCD
            gemm_fast<0, 1, 128, 64><<<gg1, 512, 0, stream>>>(Wpad, featPad, Nvp,
                (__hip_bfloat16*)hT, Nvp, nullptr, nullptr, nullptr, 0, 0, fdt);
        } else {
            dim3 gg1f(Nvp / 128, 8);
            gemm1_raw<<<gg1f, 256, 0, stream>>>(d_in[W_I[v]], d_in[FEAT_I[v]], Kp,
                                                Nv, Nv, 901, Nv, Nv,
                                                (__hip_bfloat16*)hT, Nvp, fdt);
        }

        // zero asrc+adst+lrow in one shot (contiguous: 3968+3968+1792 floats)
        zerof<<<38, 256, 0, stream>>>(asrc, 3968 + 3968 + 1792);

        dim3 gsd((Nv + 255) / 256, 8);
        srcdst2<<<gsd, 256, 0, stream>>>((const __hip_bfloat16*)hT,
            d_in[AS_I[v]], d_in[AD_I[v]], Nv, Nvp, asrc, adst, fdt);

        dim3 gp(Nvp / 64, 28);
        pbuild<<<gp, 256, 0, stream>>>((const int*)d_in[ADJ_I[v]], asrc, adst, Nv, Nvp, ioff2,
                                       (__hip_bfloat16*)Pexp, lrow);

        // vout[1778,901] = relu(P·h / l + b) ; BM=64,BN=64 -> grid 448
        dim3 gg2(16, 28);
        // A (Pexp) is the big operand -> cluster same-y per XCD
        gemm_fast<1, 0, 64, 64><<<gg2, 256, 0, stream>>>(Pexp, hT, Nvp,
            nullptr, 0, lrow, d_in[BV_I[v]], voutb[v], NROWS, OUTF, fdt);
    }

    cam_pass1<<<CAMNB, 256, 0, stream>>>(voutb[0], voutb[1], voutb[2], d_in[7],
        d_in[20], d_in[21], d_in[24], d_in[25], cp1, fdt);
    cam_fin1<<<1, 256, 0, stream>>>(cp1, statsF);
    cam_pass2<<<CAMNB, 256, 0, stream>>>(voutb[0], voutb[1], voutb[2], d_in[7],
        d_in[20], d_in[21], d_in[24], d_in[25], statsF, cp2, fdt);
    cam_fin2<<<1, 256, 0, stream>>>(cp2, statsF, d_in[22], d_in[26], fdt);
    cam_fuse<<<CAMNB, 256, 0, stream>>>(voutb[0], voutb[1], voutb[2], d_in[7],
        d_in[20], d_in[21], d_in[24], d_in[25], statsF, sumx, fdt);

    // collapsed MLP head, parallelized
    mlp_a<<<1, 256, 0, stream>>>(d_in[32], d_in[34], d_in[31], d_in[33], d_in[35],
                                 u3g, u2g, statsF, fdt);
    mlp_b1<<<dim3(4, 8), 256, 0, stream>>>(d_in[30], u2g, part1, fdt);
    mlp_b2<<<4, 256, 0, stream>>>(part1, u1);
    mlp_c<<<1, 256, 0, stream>>>(d_in[29], u1, statsF, fdt);
    mlp_u0s1<<<dim3(8, 16), 256, 0, stream>>>(d_in[28], u1, part0, fdt);
    mlp_u0s2<<<8, 256, 0, stream>>>(part0, u0);

    rowdot<<<NROWS, 256, 0, stream>>>(sumx, u0, fv, gv);
    score<<<16, 256, 0, stream>>>((const int*)d_in[3], fv, gv, statsF, d_out, fdt);
}